// Round 6
// baseline (537.555 us; speedup 1.0000x reference)
//
#include <hip/hip_runtime.h>
#include <math.h>

// W=4096, D=768, K=768, SPAN=3D=2304, F=20, H=1000, PAIR=6932, C=50.
#define WTOK 4096
#define DD   768
#define KK   768
#define SPAN 2304
#define HH   1000
#define CC   50
#define NPAD 1024   // HH padded for pair-GEMM tiles
#define NBIG 4352   // 2304 (coarse) + 1024 (tgt) + 1024 (ant)

typedef __attribute__((ext_vector_type(8))) short bf16x8;
typedef __attribute__((ext_vector_type(4))) float f32x4;
typedef unsigned short ushort;
typedef unsigned int uint;

__device__ __forceinline__ int bucketd(int d) {
  int l = (d >= 1) ? (31 - __clz(d)) : 0;
  int v = (d <= 4) ? d : (l + 3);
  return min(max(v, 0), 9);
}
__device__ __forceinline__ ushort f2bf(float f) {
  uint u = __float_as_uint(f);
  return (ushort)((u + 0x7fffu + ((u >> 16) & 1u)) >> 16);  // RNE
}
// packed bf16x2 elementwise product, truncating round.
// Pack via v_perm_b32: out = {hi.b3, hi.b2, lo.b3, lo.b2} == (lo>>16)|(hi&0xffff0000)
__device__ __forceinline__ uint pkmul_t(uint a, uint b) {
  float lo = __uint_as_float(a << 16) * __uint_as_float(b << 16);
  float hi = __uint_as_float(a & 0xffff0000u) * __uint_as_float(b & 0xffff0000u);
  return __builtin_amdgcn_perm(__float_as_uint(hi), __float_as_uint(lo), 0x07060302u);
}
__device__ __forceinline__ uint4 pkmul4(uint4 a, uint4 b) {
  uint4 r;
  r.x = pkmul_t(a.x, b.x); r.y = pkmul_t(a.y, b.y);
  r.z = pkmul_t(a.z, b.z); r.w = pkmul_t(a.w, b.w);
  return r;
}
// async global->LDS DMA, 16 B per lane; LDS dest = firstlane base + lane*16
__device__ __forceinline__ void dma16(const ushort* g, ushort* l) {
  __builtin_amdgcn_global_load_lds(
      (const __attribute__((address_space(1))) void*)g,
      (__attribute__((address_space(3))) void*)l, 16, 0, 0);
}

// ---------------------------------------------------------------------------
// K0: fused prep: transposes (k-tiled [72][rows][32]), dist setup, slow init
// ---------------------------------------------------------------------------
#define PB_COARSE 5184
#define PB_W 2304
#define PB_SETUP_BASE (PB_COARSE + 3 * PB_W)          // 12096
#define PB_SLOW_BASE  (PB_SETUP_BASE + 40)            // 12136
#define PB_TOTAL      (PB_SLOW_BASE + 150)            // 12286

__global__ __launch_bounds__(256) void prep_k(
    const float* __restrict__ coarse_w, const float* __restrict__ W1,
    const float* __restrict__ dist_prior, const float* __restrict__ dist_w,
    const float* __restrict__ dist_b, const float* __restrict__ top_dist,
    ushort* __restrict__ BigT, ushort* __restrict__ W1simT,
    float* __restrict__ dist_score, float* __restrict__ Pdist,
    float* __restrict__ slow)
{
  int bid = blockIdx.x;
  int tid = threadIdx.x;
  if (bid >= PB_SLOW_BASE) {
    int t = (bid - PB_SLOW_BASE) * 256 + tid;
    if (t < KK * CC) slow[t] = 0.f;
    return;
  }
  if (bid >= PB_SETUP_BASE) {
    int t = (bid - PB_SETUP_BASE) * 256 + tid;
    if (t < 10) {
      float s = dist_b[0];
      for (int f = 0; f < 20; ++f) s += dist_prior[t * 20 + f] * dist_w[f];
      dist_score[t] = s;
    }
    if (t < 10 * HH) {
      int b = t / HH, h = t % HH;
      float s = 0.f;
      for (int f = 0; f < 20; ++f)
        s += top_dist[b * 20 + f] * W1[(long)(6912 + f) * HH + h];
      Pdist[t] = s;
    }
    return;
  }
  const float* in; int ldin, Cin, nbase, NBrows; ushort* out; int idx;
  int xt;
  if (bid < PB_COARSE) {
    idx = bid; in = coarse_w; ldin = SPAN; Cin = SPAN; nbase = 0;
    NBrows = NBIG; out = BigT; xt = SPAN / 32;
  } else {
    idx = bid - PB_COARSE;
    int region = idx / PB_W;  // 0=tgt 1=ant 2=sim
    idx = idx % PB_W;
    if (region == 0) { in = W1; nbase = 2304; NBrows = NBIG; out = BigT; }
    else if (region == 1) { in = W1 + (size_t)SPAN * HH; nbase = 3328; NBrows = NBIG; out = BigT; }
    else { in = W1 + (size_t)2 * SPAN * HH; nbase = 0; NBrows = NPAD; out = W1simT; }
    ldin = HH; Cin = HH; xt = NPAD / 32;
  }
  {
    int bx = idx % xt, by = idx / xt;
    __shared__ float tile[32][33];
    int n0 = bx * 32, p0 = by * 32;
    int tx = tid & 31, ty = tid >> 5;
    for (int i = ty; i < 32; i += 8) {
      int p = p0 + i, n = n0 + tx;
      tile[i][tx] = (n < Cin) ? in[(long)p * ldin + n] : 0.f;
    }
    __syncthreads();
    size_t slab = (size_t)(p0 >> 5) * NBrows * 32;
    for (int i = ty; i < 32; i += 8) {
      int n = n0 + i;
      out[slab + (size_t)(nbase + n) * 32 + tx] = f2bf(tile[tx][i]);
    }
  }
}

// ---------------------------------------------------------------------------
// K1: hybrid doc + token attention logits
// ---------------------------------------------------------------------------
__global__ __launch_bounds__(256) void hybrid_attn_k(
    const float* __restrict__ doc, const float* __restrict__ doc1,
    const float* __restrict__ attn_w, const float* __restrict__ attn_b,
    float* __restrict__ hybrid, float* __restrict__ tok_attn)
{
  int w = blockIdx.x;
  int tid = threadIdx.x;
  float part = 0.f;
  for (int d = tid; d < DD; d += 256) {
    float h = 0.5f * doc[(long)w * DD + d] + 0.5f * doc1[(long)w * DD + d];
    hybrid[(long)w * DD + d] = h;
    part += h * attn_w[d];
  }
  for (int off = 32; off > 0; off >>= 1) part += __shfl_down(part, off, 64);
  __shared__ float ws4[4];
  if ((tid & 63) == 0) ws4[tid >> 6] = part;
  __syncthreads();
  if (tid == 0) tok_attn[w] = ws4[0] + ws4[1] + ws4[2] + ws4[3] + attn_b[0];
}

// ---------------------------------------------------------------------------
// K2: span embeddings -> se_bf [KK][SPAN] bf16
// ---------------------------------------------------------------------------
__global__ __launch_bounds__(256) void span_emb_k(
    const float* __restrict__ doc, const float* __restrict__ hybrid,
    const float* __restrict__ tok_attn, const int* __restrict__ starts,
    const int* __restrict__ ends, ushort* __restrict__ se_bf)
{
  int k = blockIdx.x;
  int s = starts[k], e = ends[k];
  int len = e - s + 1;  // <= 30
  int tid = threadIdx.x;
  __shared__ float p_s[32];
  if (tid < 32) {
    float v = (tid < len) ? tok_attn[s + tid] : -INFINITY;
    float m = v;
    for (int msk = 16; msk >= 1; msk >>= 1) m = fmaxf(m, __shfl_xor(m, msk, 32));
    float pe = (tid < len) ? expf(v - m) : 0.f;
    float Z = pe;
    for (int msk = 16; msk >= 1; msk >>= 1) Z += __shfl_xor(Z, msk, 32);
    p_s[tid] = pe / Z;
  }
  __syncthreads();
  for (int d = tid; d < DD; d += 256) {
    float h = 0.f;
    for (int t = 0; t < len; ++t) h += p_s[t] * hybrid[(long)(s + t) * DD + d];
    se_bf[(long)k * SPAN + d]          = f2bf(doc[(long)s * DD + d]);
    se_bf[(long)k * SPAN + DD + d]     = f2bf(doc[(long)e * DD + d]);
    se_bf[(long)k * SPAN + 2 * DD + d] = f2bf(h);
  }
}

// ---------------------------------------------------------------------------
// K3: combined NT GEMM, 64x128 tiles. A = se_bf shared; routed epilogue
// [src | Ptgt+b1 | Pant]. B via DMA, swizzled unpadded. (unchanged)
// ---------------------------------------------------------------------------
__global__ __launch_bounds__(256) void gemm_combined_k(
    const ushort* __restrict__ A, const ushort* __restrict__ B,
    const float* __restrict__ coarse_b, const float* __restrict__ b1,
    ushort* __restrict__ src_bf, float* __restrict__ Ptgt,
    float* __restrict__ Pant)
{
  __shared__ __align__(16) ushort As[64 * 40];
  __shared__ __align__(16) ushort Bs[128 * 32];
  int tid = threadIdx.x;
  int m0 = blockIdx.x * 64, n0 = blockIdx.y * 128;
  int lane = tid & 63, wid = tid >> 6;
  int quad = lane >> 4, lr = lane & 15;
  int wm = (wid & 1) << 5, wn = (wid >> 1) << 6;
  int arow = tid >> 2, aq = tid & 3;     // A: 64 rows, 4 lanes each
  int gofs[2];
#pragma unroll
  for (int t = 0; t < 2; ++t) {
    int S = t * 256 + tid;
    int r = S >> 2, p = S & 3;
    int q = p ^ ((r >> 1) & 3);
    gofs[t] = (n0 + r) * 32 + q * 8;
  }
  f32x4 acc[2][4] = {};
  for (int k0 = 0; k0 < SPAN; k0 += 32) {
    uint4 a0 = *(const uint4*)(A + (size_t)(m0 + arow) * SPAN + k0 + aq * 8);
    __syncthreads();
    const ushort* sb = B + (size_t)(k0 >> 5) * (NBIG * 32);
    dma16(sb + gofs[0], &Bs[(size_t)(0 * 256 + tid) * 8]);
    dma16(sb + gofs[1], &Bs[(size_t)(1 * 256 + tid) * 8]);
    *(uint4*)&As[arow * 40 + aq * 8] = a0;
    __syncthreads();
    bf16x8 af[2], bfr[4];
#pragma unroll
    for (int mi = 0; mi < 2; ++mi)
      af[mi] = *(const bf16x8*)&As[(wm + mi * 16 + lr) * 40 + quad * 8];
#pragma unroll
    for (int ni = 0; ni < 4; ++ni) {
      int r = wn + ni * 16 + lr;
      int p = quad ^ ((r >> 1) & 3);
      bfr[ni] = *(const bf16x8*)&Bs[r * 32 + p * 8];
    }
#pragma unroll
    for (int mi = 0; mi < 2; ++mi)
#pragma unroll
      for (int ni = 0; ni < 4; ++ni)
        acc[mi][ni] = __builtin_amdgcn_mfma_f32_16x16x32_bf16(
            af[mi], bfr[ni], acc[mi][ni], 0, 0, 0);
  }
#pragma unroll
  for (int mi = 0; mi < 2; ++mi)
#pragma unroll
    for (int ni = 0; ni < 4; ++ni) {
      f32x4 c = acc[mi][ni];
#pragma unroll
      for (int reg = 0; reg < 4; ++reg) {
        int gm = m0 + wm + mi * 16 + quad * 4 + reg;
        int g = n0 + wn + ni * 16 + lr;
        float v = c[reg];
        if (g < 2304) {
          src_bf[(size_t)gm * SPAN + g] = f2bf(v + coarse_b[g]);
        } else if (g < 3328) {
          int n = g - 2304;
          if (n < HH) Ptgt[(size_t)gm * HH + n] = v + b1[n];  // b1 folded in
        } else {
          int n = g - 3328;
          if (n < HH) Pant[(size_t)gm * HH + n] = v;
        }
      }
    }
}

// ---------------------------------------------------------------------------
// K4: fast GEMM (src @ se^T), 64x64 tiles, fused epilogue (unchanged)
// ---------------------------------------------------------------------------
__global__ __launch_bounds__(256) void gemm_fast_k(
    const ushort* __restrict__ A, const ushort* __restrict__ B,
    const float* __restrict__ ms, const float* __restrict__ dist_score,
    float* __restrict__ fast)
{
  __shared__ __align__(16) ushort As[64 * 40];
  __shared__ __align__(16) ushort Bs[64 * 40];
  int tid = threadIdx.x;
  int m0 = blockIdx.x * 64, n0 = blockIdx.y * 64;
  int lane = tid & 63, wid = tid >> 6;
  int quad = lane >> 4, lr = lane & 15;
  int wm = (wid & 1) << 5, wn = (wid >> 1) << 5;
  int row = tid >> 2, aq = tid & 3;
  const ushort* ga = A + (size_t)(m0 + row) * SPAN + aq * 8;
  const ushort* gb = B + (size_t)(n0 + row) * SPAN + aq * 8;
  f32x4 acc[2][2] = {};
  for (int k0 = 0; k0 < SPAN; k0 += 32) {
    uint4 a0 = *(const uint4*)(ga + k0);
    uint4 b0 = *(const uint4*)(gb + k0);
    __syncthreads();
    *(uint4*)&As[row * 40 + aq * 8] = a0;
    *(uint4*)&Bs[row * 40 + aq * 8] = b0;
    __syncthreads();
    bf16x8 af[2], bfr[2];
#pragma unroll
    for (int mi = 0; mi < 2; ++mi)
      af[mi] = *(const bf16x8*)&As[(wm + mi * 16 + lr) * 40 + quad * 8];
#pragma unroll
    for (int ni = 0; ni < 2; ++ni)
      bfr[ni] = *(const bf16x8*)&Bs[(wn + ni * 16 + lr) * 40 + quad * 8];
#pragma unroll
    for (int mi = 0; mi < 2; ++mi)
#pragma unroll
      for (int ni = 0; ni < 2; ++ni)
        acc[mi][ni] = __builtin_amdgcn_mfma_f32_16x16x32_bf16(
            af[mi], bfr[ni], acc[mi][ni], 0, 0, 0);
  }
#pragma unroll
  for (int mi = 0; mi < 2; ++mi)
#pragma unroll
    for (int ni = 0; ni < 2; ++ni) {
      f32x4 c = acc[mi][ni];
#pragma unroll
      for (int reg = 0; reg < 4; ++reg) {
        int gm = m0 + wm + mi * 16 + quad * 4 + reg;
        int gn = n0 + wn + ni * 16 + lr;
        float v;
        if (gn < gm) {
          v = c[reg] + ms[gm] + ms[gn] + dist_score[bucketd(gm - gn)];
        } else {
          v = -INFINITY;
        }
        fast[(size_t)gm * KK + gn] = v;
      }
    }
}

// ---------------------------------------------------------------------------
// K5: exact top-50 per row (descending, ties -> lower index)
// ---------------------------------------------------------------------------
__global__ __launch_bounds__(256) void topk_k(
    const float* __restrict__ fast, float* __restrict__ top_fast,
    int* __restrict__ row_j, int* __restrict__ row_bucket)
{
  __shared__ float vals[KK];
  __shared__ float wbv[4];
  __shared__ int wbi[4];
  int k = blockIdx.x;
  int tid = threadIdx.x;
  for (int j = tid; j < KK; j += 256) vals[j] = fast[(long)k * KK + j];
  __syncthreads();
  const float NANF = __uint_as_float(0x7fc00000u);
  for (int it = 0; it < CC; ++it) {
    float bv = -INFINITY;
    int bi = 1 << 30;
    for (int j = tid; j < KK; j += 256) {
      float v = vals[j];
      if (v > bv || (v == bv && j < bi)) { bv = v; bi = j; }
    }
    for (int off = 32; off > 0; off >>= 1) {
      float ov = __shfl_down(bv, off, 64);
      int oi = __shfl_down(bi, off, 64);
      if (ov > bv || (ov == bv && oi < bi)) { bv = ov; bi = oi; }
    }
    if ((tid & 63) == 0) { wbv[tid >> 6] = bv; wbi[tid >> 6] = bi; }
    __syncthreads();
    if (tid == 0) {
      for (int w = 1; w < 4; ++w) {
        float ov = wbv[w]; int oi = wbi[w];
        if (ov > bv || (ov == bv && oi < bi)) { bv = ov; bi = oi; }
      }
      int r = k * CC + it;
      top_fast[r] = bv;
      row_j[r] = bi;
      row_bucket[r] = bucketd(k - bi);
      vals[bi] = NANF;
    }
    __syncthreads();
  }
}

// ---------------------------------------------------------------------------
// K6: pair GEMM — fused structure (R5, proven), retiled BM=64 x BN=512,
// 512 threads, 8 waves each with a 64m x 64n tile (acc[4][4]).
// R5 counters: VALUBusy 35 ~ MfmaUtil 34, LDS-read traffic (10 b128/thr/
// K-step) > matrix-pipe time. This tile:
//  - A-panel pkmul recompute 4x -> 2x (NPAD/BN); only waves 0-3 stage A
//    (avg 0.5 pkmul4/thread, was 1) and A global loads halve.
//  - per-thread ds_reads 10 -> 8 (4 A + 4 B): -20% LDS read traffic.
//  - LDS 74.5 KB -> 2 blocks/CU (16 waves/CU >= R5's measured ~12).
// Per-element MFMA K-sequence unchanged -> numerics identical to R5.
// Cost: B restaged per 64-row m-block (DMA x2, absorbed by L2).
// ---------------------------------------------------------------------------
__global__ __launch_bounds__(512, 4) void pair_mfma_k(
    const ushort* __restrict__ se_bf, const ushort* __restrict__ W1simT,
    const int* __restrict__ row_j, const int* __restrict__ row_bucket,
    const float* __restrict__ Ptgt, const float* __restrict__ Pant,
    const float* __restrict__ Pdist, const float* __restrict__ w2,
    float* __restrict__ slow)
{
  __shared__ __align__(16) ushort As[2][64 * 32];    // 8 KB
  __shared__ __align__(16) ushort Bs[2][512 * 32];   // 64 KB
  __shared__ int ks_s[64];
  __shared__ int js_s[64];
  __shared__ int bk_s[64];
  int tid = threadIdx.x;                 // 0..511
  int m0 = blockIdx.x * 64, n0 = blockIdx.y * 512;
  if (tid < 64) {
    int r = m0 + tid;
    ks_s[tid] = r / CC;
    js_s[tid] = row_j[r];
    bk_s[tid] = row_bucket[r];
  }
  __syncthreads();
  int lane = tid & 63, wid = tid >> 6;   // 8 waves
  int quad = lane >> 4, lr = lane & 15;
  int wn = wid << 6;                     // 0..448; all waves at wm=0
  int ar0 = (tid >> 2) & 63, aq = tid & 3;  // A staging: threads 0..255
  bool astage = tid < 256;
  const ushort* pk0 = se_bf + (size_t)ks_s[ar0] * SPAN + aq * 8;
  const ushort* pj0 = se_bf + (size_t)js_s[ar0] * SPAN + aq * 8;
  int gofs[4];
#pragma unroll
  for (int t = 0; t < 4; ++t) {
    int S = t * 512 + tid;               // 0..2047 -> 512 B-rows x 4 slots
    int r = S >> 2, p = S & 3;
    int q = p ^ ((r >> 1) & 3);
    gofs[t] = (n0 + r) * 32 + q * 8;
  }
  // swizzled A-write offset: slot = aq ^ ((row>>1)&3)
  int awi0 = ar0 * 32 + (aq ^ ((ar0 >> 1) & 3)) * 8;

  {
    uint4 ka0, ja0;
    if (astage) { ka0 = *(const uint4*)(pk0); ja0 = *(const uint4*)(pj0); }
#pragma unroll
    for (int t = 0; t < 4; ++t)
      dma16(W1simT + gofs[t], &Bs[0][(size_t)(t * 512 + tid) * 8]);
    if (astage) *(uint4*)&As[0][awi0] = pkmul4(ka0, ja0);
  }
  __syncthreads();

  f32x4 acc[4][4] = {};
  for (int k0 = 0; k0 < SPAN; k0 += 32) {
    int buf = (k0 >> 5) & 1, nb = buf ^ 1;
    bool more = (k0 + 32) < SPAN;
    int k1 = more ? k0 + 32 : k0;
    uint4 ka0, ja0;
    if (astage) { ka0 = *(const uint4*)(pk0 + k1); ja0 = *(const uint4*)(pj0 + k1); }
    if (more) {
      const ushort* sb = W1simT + (size_t)(k1 >> 5) * (NPAD * 32);
#pragma unroll
      for (int t = 0; t < 4; ++t)
        dma16(sb + gofs[t], &Bs[nb][(size_t)(t * 512 + tid) * 8]);
    }
    bf16x8 af[4], bfr[4];
#pragma unroll
    for (int mi = 0; mi < 4; ++mi) {
      int r = mi * 16 + lr;
      int p = quad ^ ((r >> 1) & 3);
      af[mi] = *(const bf16x8*)&As[buf][r * 32 + p * 8];
    }
#pragma unroll
    for (int ni = 0; ni < 4; ++ni) {
      int r = wn + ni * 16 + lr;
      int p = quad ^ ((r >> 1) & 3);
      bfr[ni] = *(const bf16x8*)&Bs[buf][r * 32 + p * 8];
    }
#pragma unroll
    for (int ni = 0; ni < 4; ++ni)
#pragma unroll
      for (int mi = 0; mi < 4; ++mi)
        acc[mi][ni] = __builtin_amdgcn_mfma_f32_16x16x32_bf16(
            af[mi], bfr[ni], acc[mi][ni], 0, 0, 0);
    if (more && astage) {
      *(uint4*)&As[nb][awi0] = pkmul4(ka0, ja0);
    }
    __syncthreads();
  }
  int nn[4]; float w2r[4]; bool nv[4];
#pragma unroll
  for (int ni = 0; ni < 4; ++ni) {
    nn[ni] = n0 + wn + ni * 16 + lr;
    nv[ni] = nn[ni] < HH;
    w2r[ni] = nv[ni] ? w2[nn[ni]] : 0.f;
  }
#pragma unroll
  for (int mi = 0; mi < 4; ++mi) {
#pragma unroll
    for (int reg = 0; reg < 4; ++reg) {
      int rl = mi * 16 + quad * 4 + reg;
      int kk = ks_s[rl], jj = js_s[rl], bb = bk_s[rl];
      float s = 0.f;
#pragma unroll
      for (int ni = 0; ni < 4; ++ni) {
        if (nv[ni]) {
          float h = acc[mi][ni][reg] + Ptgt[(size_t)kk * HH + nn[ni]] +
                    Pant[(size_t)jj * HH + nn[ni]] +
                    Pdist[(size_t)bb * HH + nn[ni]];
          s += fmaxf(h, 0.f) * w2r[ni];
        }
      }
      s += __shfl_xor(s, 1); s += __shfl_xor(s, 2);
      s += __shfl_xor(s, 4); s += __shfl_xor(s, 8);
      if (lr == 0) atomicAdd(&slow[m0 + rl], s);
    }
  }
}

// ---------------------------------------------------------------------------
// K7: finalize (-inf -> -1e30)
// ---------------------------------------------------------------------------
__global__ void finalize_k(const float* __restrict__ slow,
                           const float* __restrict__ top_fast,
                           const float* __restrict__ b2, float* __restrict__ out)
{
  int t = blockIdx.x * 256 + threadIdx.x;
  if (t >= KK * (CC + 1)) return;
  int k = t / (CC + 1), col = t % (CC + 1);
  if (col == 0) {
    out[t] = 0.f;
  } else {
    int r = k * CC + col - 1;
    float v = slow[r] + b2[0] + top_fast[r];
    if (!isfinite(v)) v = -1.0e30f;
    out[t] = v;
  }
}

// ---------------------------------------------------------------------------
extern "C" void kernel_launch(void* const* d_in, const int* in_sizes, int n_in,
                              void* d_out, int out_size, void* d_ws, size_t ws_size,
                              hipStream_t stream)
{
  const float* doc        = (const float*)d_in[0];
  const float* doc1       = (const float*)d_in[1];
  const int*   starts     = (const int*)d_in[2];
  const int*   ends       = (const int*)d_in[3];
  const float* ms         = (const float*)d_in[4];
  const float* attn_w     = (const float*)d_in[5];
  const float* attn_b     = (const float*)d_in[6];
  const float* coarse_w   = (const float*)d_in[7];
  const float* coarse_b   = (const float*)d_in[8];
  const float* dist_prior = (const float*)d_in[9];
  const float* dist_w     = (const float*)d_in[10];
  const float* dist_b     = (const float*)d_in[11];
  const float* top_dist   = (const float*)d_in[12];
  const float* W1         = (const float*)d_in[13];
  const float* b1         = (const float*)d_in[14];
  const float* w2         = (const float*)d_in[15];
  const float* b2         = (const float*)d_in[16];
  float* out = (float*)d_out;

  char* ws = (char*)d_ws;
  size_t off = 0;
  auto alloc = [&](size_t bytes) { void* p = ws + off; off = (off + bytes + 1023) & ~(size_t)1023; return p; };
  float*  hybrid     = (float*)alloc((size_t)WTOK * DD * 4);
  float*  tok_attn   = (float*)alloc((size_t)WTOK * 4);
  ushort* se_bf      = (ushort*)alloc((size_t)KK * SPAN * 2 + 4096);
  ushort* src_bf     = (ushort*)alloc((size_t)KK * SPAN * 2 + 4096);
  float*  fast       = (float*)alloc((size_t)KK * KK * 4);
  float*  Ptgt       = (float*)alloc((size_t)KK * HH * 4);
  float*  Pant       = (float*)alloc((size_t)KK * HH * 4);
  float*  Pdist      = (float*)alloc((size_t)10 * HH * 4);
  float*  dist_score = (float*)alloc(64);
  float*  top_fast   = (float*)alloc((size_t)KK * CC * 4);
  int*    row_j      = (int*)alloc((size_t)KK * CC * 4);
  int*    row_bucket = (int*)alloc((size_t)KK * CC * 4);
  float*  slow       = (float*)alloc((size_t)KK * CC * 4);
  ushort* BigT       = (ushort*)alloc((size_t)NBIG * SPAN * 2 + 4096);   // k-tiled [72][NBIG][32]
  ushort* W1simT     = (ushort*)alloc((size_t)NPAD * SPAN * 2 + 4096);   // k-tiled [72][NPAD][32]
  (void)ws_size; (void)in_sizes; (void)n_in; (void)out_size;

  // 1. fused prep: transposes + dist setup + slow init
  prep_k<<<PB_TOTAL, 256, 0, stream>>>(coarse_w, W1, dist_prior, dist_w,
                                       dist_b, top_dist, BigT, W1simT,
                                       dist_score, Pdist, slow);
  // 2. hybrid + token attention
  hybrid_attn_k<<<WTOK, 256, 0, stream>>>(doc, doc1, attn_w, attn_b, hybrid, tok_attn);
  // 3. span embeddings
  span_emb_k<<<KK, 256, 0, stream>>>(doc, hybrid, tok_attn, starts, ends, se_bf);
  // 4. src_bf / Ptgt(+b1) / Pant in one launch (shared A), 64x128 tiles
  {
    dim3 g(KK / 64, NBIG / 128);
    gemm_combined_k<<<g, 256, 0, stream>>>(se_bf, BigT, coarse_b, b1,
                                           src_bf, Ptgt, Pant);
  }
  // 5. fast = src @ se^T with fused epilogue, 64x64 tiles
  {
    dim3 g(KK / 64, KK / 64);
    gemm_fast_k<<<g, 256, 0, stream>>>(src_bf, se_bf, ms, dist_score, fast);
  }
  // 6. top-50
  topk_k<<<KK, 256, 0, stream>>>(fast, top_fast, row_j, row_bucket);
  // 7. fused pair GEMM + epilogue, BM=64 x BN=512, 512 threads
  //    (x = m fastest within fixed n -> B-panel L2-resident)
  {
    dim3 g((KK * CC) / 64, NPAD / 512);
    pair_mfma_k<<<g, 512, 0, stream>>>(se_bf, W1simT, row_j, row_bucket,
                                       Ptgt, Pant, Pdist, w2, slow);
  }
  // 8. output
  finalize_k<<<(KK * (CC + 1) + 255) / 256, 256, 0, stream>>>(slow, top_fast, b2, out);
}

// Round 7
// 530.334 us; speedup vs baseline: 1.0136x; 1.0136x over previous
//
#include <hip/hip_runtime.h>
#include <math.h>

// W=4096, D=768, K=768, SPAN=3D=2304, F=20, H=1000, PAIR=6932, C=50.
#define WTOK 4096
#define DD   768
#define KK   768
#define SPAN 2304
#define HH   1000
#define CC   50
#define NPAD 1024   // HH padded for pair-GEMM tiles
#define NBIG 4352   // 2304 (coarse) + 1024 (tgt) + 1024 (ant)

typedef __attribute__((ext_vector_type(8))) short bf16x8;
typedef __attribute__((ext_vector_type(4))) float f32x4;
typedef unsigned short ushort;
typedef unsigned int uint;

__device__ __forceinline__ int bucketd(int d) {
  int l = (d >= 1) ? (31 - __clz(d)) : 0;
  int v = (d <= 4) ? d : (l + 3);
  return min(max(v, 0), 9);
}
__device__ __forceinline__ ushort f2bf(float f) {
  uint u = __float_as_uint(f);
  return (ushort)((u + 0x7fffu + ((u >> 16) & 1u)) >> 16);  // RNE
}
// packed bf16x2 elementwise product, truncating round.
// Pack via v_perm_b32: out = {hi.b3, hi.b2, lo.b3, lo.b2} == (lo>>16)|(hi&0xffff0000)
__device__ __forceinline__ uint pkmul_t(uint a, uint b) {
  float lo = __uint_as_float(a << 16) * __uint_as_float(b << 16);
  float hi = __uint_as_float(a & 0xffff0000u) * __uint_as_float(b & 0xffff0000u);
  return __builtin_amdgcn_perm(__float_as_uint(hi), __float_as_uint(lo), 0x07060302u);
}
__device__ __forceinline__ uint4 pkmul4(uint4 a, uint4 b) {
  uint4 r;
  r.x = pkmul_t(a.x, b.x); r.y = pkmul_t(a.y, b.y);
  r.z = pkmul_t(a.z, b.z); r.w = pkmul_t(a.w, b.w);
  return r;
}
// async global->LDS DMA, 16 B per lane; LDS dest = firstlane base + lane*16
__device__ __forceinline__ void dma16(const ushort* g, ushort* l) {
  __builtin_amdgcn_global_load_lds(
      (const __attribute__((address_space(1))) void*)g,
      (__attribute__((address_space(3))) void*)l, 16, 0, 0);
}

// ---------------------------------------------------------------------------
// K0: fused prep: transposes (k-tiled [72][rows][32]), dist setup, slow init,
// + hybrid/token-attn tail (independent work merged to fill the grid tail).
// ---------------------------------------------------------------------------
#define PB_COARSE 5184
#define PB_W 2304
#define PB_SETUP_BASE (PB_COARSE + 3 * PB_W)          // 12096
#define PB_SLOW_BASE  (PB_SETUP_BASE + 40)            // 12136
#define PB_HYB_BASE   (PB_SLOW_BASE + 150)            // 12286
#define PB_TOTAL      (PB_HYB_BASE + WTOK)            // 16382

__global__ __launch_bounds__(256) void prep_k(
    const float* __restrict__ coarse_w, const float* __restrict__ W1,
    const float* __restrict__ dist_prior, const float* __restrict__ dist_w,
    const float* __restrict__ dist_b, const float* __restrict__ top_dist,
    const float* __restrict__ doc, const float* __restrict__ doc1,
    const float* __restrict__ attn_w, const float* __restrict__ attn_b,
    ushort* __restrict__ BigT, ushort* __restrict__ W1simT,
    float* __restrict__ dist_score, float* __restrict__ Pdist,
    float* __restrict__ slow, float* __restrict__ hybrid,
    float* __restrict__ tok_attn)
{
  int bid = blockIdx.x;
  int tid = threadIdx.x;
  if (bid >= PB_HYB_BASE) {
    // hybrid doc + token attention logits (one block per token)
    int w = bid - PB_HYB_BASE;
    float part = 0.f;
    for (int d = tid; d < DD; d += 256) {
      float h = 0.5f * doc[(long)w * DD + d] + 0.5f * doc1[(long)w * DD + d];
      hybrid[(long)w * DD + d] = h;
      part += h * attn_w[d];
    }
    for (int off = 32; off > 0; off >>= 1) part += __shfl_down(part, off, 64);
    __shared__ float ws4[4];
    if ((tid & 63) == 0) ws4[tid >> 6] = part;
    __syncthreads();
    if (tid == 0) tok_attn[w] = ws4[0] + ws4[1] + ws4[2] + ws4[3] + attn_b[0];
    return;
  }
  if (bid >= PB_SLOW_BASE) {
    int t = (bid - PB_SLOW_BASE) * 256 + tid;
    if (t < KK * CC) slow[t] = 0.f;
    return;
  }
  if (bid >= PB_SETUP_BASE) {
    int t = (bid - PB_SETUP_BASE) * 256 + tid;
    if (t < 10) {
      float s = dist_b[0];
      for (int f = 0; f < 20; ++f) s += dist_prior[t * 20 + f] * dist_w[f];
      dist_score[t] = s;
    }
    if (t < 10 * HH) {
      int b = t / HH, h = t % HH;
      float s = 0.f;
      for (int f = 0; f < 20; ++f)
        s += top_dist[b * 20 + f] * W1[(long)(6912 + f) * HH + h];
      Pdist[t] = s;
    }
    return;
  }
  const float* in; int ldin, Cin, nbase, NBrows; ushort* out; int idx;
  int xt;
  if (bid < PB_COARSE) {
    idx = bid; in = coarse_w; ldin = SPAN; Cin = SPAN; nbase = 0;
    NBrows = NBIG; out = BigT; xt = SPAN / 32;
  } else {
    idx = bid - PB_COARSE;
    int region = idx / PB_W;  // 0=tgt 1=ant 2=sim
    idx = idx % PB_W;
    if (region == 0) { in = W1; nbase = 2304; NBrows = NBIG; out = BigT; }
    else if (region == 1) { in = W1 + (size_t)SPAN * HH; nbase = 3328; NBrows = NBIG; out = BigT; }
    else { in = W1 + (size_t)2 * SPAN * HH; nbase = 0; NBrows = NPAD; out = W1simT; }
    ldin = HH; Cin = HH; xt = NPAD / 32;
  }
  {
    int bx = idx % xt, by = idx / xt;
    __shared__ float tile[32][33];
    int n0 = bx * 32, p0 = by * 32;
    int tx = tid & 31, ty = tid >> 5;
    for (int i = ty; i < 32; i += 8) {
      int p = p0 + i, n = n0 + tx;
      tile[i][tx] = (n < Cin) ? in[(long)p * ldin + n] : 0.f;
    }
    __syncthreads();
    size_t slab = (size_t)(p0 >> 5) * NBrows * 32;
    for (int i = ty; i < 32; i += 8) {
      int n = n0 + i;
      out[slab + (size_t)(nbase + n) * 32 + tx] = f2bf(tile[tx][i]);
    }
  }
}

// ---------------------------------------------------------------------------
// K2: span embeddings -> se_bf [KK][SPAN] bf16
// ---------------------------------------------------------------------------
__global__ __launch_bounds__(256) void span_emb_k(
    const float* __restrict__ doc, const float* __restrict__ hybrid,
    const float* __restrict__ tok_attn, const int* __restrict__ starts,
    const int* __restrict__ ends, ushort* __restrict__ se_bf)
{
  int k = blockIdx.x;
  int s = starts[k], e = ends[k];
  int len = e - s + 1;  // <= 30
  int tid = threadIdx.x;
  __shared__ float p_s[32];
  if (tid < 32) {
    float v = (tid < len) ? tok_attn[s + tid] : -INFINITY;
    float m = v;
    for (int msk = 16; msk >= 1; msk >>= 1) m = fmaxf(m, __shfl_xor(m, msk, 32));
    float pe = (tid < len) ? expf(v - m) : 0.f;
    float Z = pe;
    for (int msk = 16; msk >= 1; msk >>= 1) Z += __shfl_xor(Z, msk, 32);
    p_s[tid] = pe / Z;
  }
  __syncthreads();
  for (int d = tid; d < DD; d += 256) {
    float h = 0.f;
    for (int t = 0; t < len; ++t) h += p_s[t] * hybrid[(long)(s + t) * DD + d];
    se_bf[(long)k * SPAN + d]          = f2bf(doc[(long)s * DD + d]);
    se_bf[(long)k * SPAN + DD + d]     = f2bf(doc[(long)e * DD + d]);
    se_bf[(long)k * SPAN + 2 * DD + d] = f2bf(h);
  }
}

// ---------------------------------------------------------------------------
// K3: combined NT GEMM, 64x128 tiles. A = se_bf shared; routed epilogue
// [src | Ptgt+b1 | Pant]. B via DMA, swizzled unpadded. (unchanged)
// ---------------------------------------------------------------------------
__global__ __launch_bounds__(256) void gemm_combined_k(
    const ushort* __restrict__ A, const ushort* __restrict__ B,
    const float* __restrict__ coarse_b, const float* __restrict__ b1,
    ushort* __restrict__ src_bf, float* __restrict__ Ptgt,
    float* __restrict__ Pant)
{
  __shared__ __align__(16) ushort As[64 * 40];
  __shared__ __align__(16) ushort Bs[128 * 32];
  int tid = threadIdx.x;
  int m0 = blockIdx.x * 64, n0 = blockIdx.y * 128;
  int lane = tid & 63, wid = tid >> 6;
  int quad = lane >> 4, lr = lane & 15;
  int wm = (wid & 1) << 5, wn = (wid >> 1) << 6;
  int arow = tid >> 2, aq = tid & 3;     // A: 64 rows, 4 lanes each
  int gofs[2];
#pragma unroll
  for (int t = 0; t < 2; ++t) {
    int S = t * 256 + tid;
    int r = S >> 2, p = S & 3;
    int q = p ^ ((r >> 1) & 3);
    gofs[t] = (n0 + r) * 32 + q * 8;
  }
  f32x4 acc[2][4] = {};
  for (int k0 = 0; k0 < SPAN; k0 += 32) {
    uint4 a0 = *(const uint4*)(A + (size_t)(m0 + arow) * SPAN + k0 + aq * 8);
    __syncthreads();
    const ushort* sb = B + (size_t)(k0 >> 5) * (NBIG * 32);
    dma16(sb + gofs[0], &Bs[(size_t)(0 * 256 + tid) * 8]);
    dma16(sb + gofs[1], &Bs[(size_t)(1 * 256 + tid) * 8]);
    *(uint4*)&As[arow * 40 + aq * 8] = a0;
    __syncthreads();
    bf16x8 af[2], bfr[4];
#pragma unroll
    for (int mi = 0; mi < 2; ++mi)
      af[mi] = *(const bf16x8*)&As[(wm + mi * 16 + lr) * 40 + quad * 8];
#pragma unroll
    for (int ni = 0; ni < 4; ++ni) {
      int r = wn + ni * 16 + lr;
      int p = quad ^ ((r >> 1) & 3);
      bfr[ni] = *(const bf16x8*)&Bs[r * 32 + p * 8];
    }
#pragma unroll
    for (int mi = 0; mi < 2; ++mi)
#pragma unroll
      for (int ni = 0; ni < 4; ++ni)
        acc[mi][ni] = __builtin_amdgcn_mfma_f32_16x16x32_bf16(
            af[mi], bfr[ni], acc[mi][ni], 0, 0, 0);
  }
#pragma unroll
  for (int mi = 0; mi < 2; ++mi)
#pragma unroll
    for (int ni = 0; ni < 4; ++ni) {
      f32x4 c = acc[mi][ni];
#pragma unroll
      for (int reg = 0; reg < 4; ++reg) {
        int gm = m0 + wm + mi * 16 + quad * 4 + reg;
        int g = n0 + wn + ni * 16 + lr;
        float v = c[reg];
        if (g < 2304) {
          src_bf[(size_t)gm * SPAN + g] = f2bf(v + coarse_b[g]);
        } else if (g < 3328) {
          int n = g - 2304;
          if (n < HH) Ptgt[(size_t)gm * HH + n] = v + b1[n];  // b1 folded in
        } else {
          int n = g - 3328;
          if (n < HH) Pant[(size_t)gm * HH + n] = v;
        }
      }
    }
}

// ---------------------------------------------------------------------------
// K4: fast GEMM (src @ se^T), 64x64 tiles, fused epilogue (unchanged)
// ---------------------------------------------------------------------------
__global__ __launch_bounds__(256) void gemm_fast_k(
    const ushort* __restrict__ A, const ushort* __restrict__ B,
    const float* __restrict__ ms, const float* __restrict__ dist_score,
    float* __restrict__ fast)
{
  __shared__ __align__(16) ushort As[64 * 40];
  __shared__ __align__(16) ushort Bs[64 * 40];
  int tid = threadIdx.x;
  int m0 = blockIdx.x * 64, n0 = blockIdx.y * 64;
  int lane = tid & 63, wid = tid >> 6;
  int quad = lane >> 4, lr = lane & 15;
  int wm = (wid & 1) << 5, wn = (wid >> 1) << 5;
  int row = tid >> 2, aq = tid & 3;
  const ushort* ga = A + (size_t)(m0 + row) * SPAN + aq * 8;
  const ushort* gb = B + (size_t)(n0 + row) * SPAN + aq * 8;
  f32x4 acc[2][2] = {};
  for (int k0 = 0; k0 < SPAN; k0 += 32) {
    uint4 a0 = *(const uint4*)(ga + k0);
    uint4 b0 = *(const uint4*)(gb + k0);
    __syncthreads();
    *(uint4*)&As[row * 40 + aq * 8] = a0;
    *(uint4*)&Bs[row * 40 + aq * 8] = b0;
    __syncthreads();
    bf16x8 af[2], bfr[2];
#pragma unroll
    for (int mi = 0; mi < 2; ++mi)
      af[mi] = *(const bf16x8*)&As[(wm + mi * 16 + lr) * 40 + quad * 8];
#pragma unroll
    for (int ni = 0; ni < 2; ++ni)
      bfr[ni] = *(const bf16x8*)&Bs[(wn + ni * 16 + lr) * 40 + quad * 8];
#pragma unroll
    for (int mi = 0; mi < 2; ++mi)
#pragma unroll
      for (int ni = 0; ni < 2; ++ni)
        acc[mi][ni] = __builtin_amdgcn_mfma_f32_16x16x32_bf16(
            af[mi], bfr[ni], acc[mi][ni], 0, 0, 0);
  }
#pragma unroll
  for (int mi = 0; mi < 2; ++mi)
#pragma unroll
    for (int ni = 0; ni < 2; ++ni) {
      f32x4 c = acc[mi][ni];
#pragma unroll
      for (int reg = 0; reg < 4; ++reg) {
        int gm = m0 + wm + mi * 16 + quad * 4 + reg;
        int gn = n0 + wn + ni * 16 + lr;
        float v;
        if (gn < gm) {
          v = c[reg] + ms[gm] + ms[gn] + dist_score[bucketd(gm - gn)];
        } else {
          v = -INFINITY;
        }
        fast[(size_t)gm * KK + gn] = v;
      }
    }
}

// ---------------------------------------------------------------------------
// K5: exact top-50 per row (descending, ties -> lower index)
// ---------------------------------------------------------------------------
__global__ __launch_bounds__(256) void topk_k(
    const float* __restrict__ fast, float* __restrict__ top_fast,
    int* __restrict__ row_j, int* __restrict__ row_bucket)
{
  __shared__ float vals[KK];
  __shared__ float wbv[4];
  __shared__ int wbi[4];
  int k = blockIdx.x;
  int tid = threadIdx.x;
  for (int j = tid; j < KK; j += 256) vals[j] = fast[(long)k * KK + j];
  __syncthreads();
  const float NANF = __uint_as_float(0x7fc00000u);
  for (int it = 0; it < CC; ++it) {
    float bv = -INFINITY;
    int bi = 1 << 30;
    for (int j = tid; j < KK; j += 256) {
      float v = vals[j];
      if (v > bv || (v == bv && j < bi)) { bv = v; bi = j; }
    }
    for (int off = 32; off > 0; off >>= 1) {
      float ov = __shfl_down(bv, off, 64);
      int oi = __shfl_down(bi, off, 64);
      if (ov > bv || (ov == bv && oi < bi)) { bv = ov; bi = oi; }
    }
    if ((tid & 63) == 0) { wbv[tid >> 6] = bv; wbi[tid >> 6] = bi; }
    __syncthreads();
    if (tid == 0) {
      for (int w = 1; w < 4; ++w) {
        float ov = wbv[w]; int oi = wbi[w];
        if (ov > bv || (ov == bv && oi < bi)) { bv = ov; bi = oi; }
      }
      int r = k * CC + it;
      top_fast[r] = bv;
      row_j[r] = bi;
      row_bucket[r] = bucketd(k - bi);
      vals[bi] = NANF;
    }
    __syncthreads();
  }
}

// ---------------------------------------------------------------------------
// K6: pair GEMM — R5 config (proven best: BM=128 x BN=256, 512 thr, dbuf,
// LDS 49.5 KB, 1 barrier/iter, 0 bank conflicts) with ONE delta: wave tiling
// 4m x 2n (32x128, 2 A + 8 B ds_reads) -> 2m x 4n (64x64, 4 A + 4 B).
// R5 cycle budget shows LDS-read throughput is the binding resource
// (~960 cy/block-K-step vs MFMA 620); this cuts wave ds_reads 10 -> 8
// (-20% on the binding pipe) with staging economics unchanged.
// Per-element MFMA k-order unchanged (1 mfma/acc/K-step) -> same numerics.
// ---------------------------------------------------------------------------
__global__ __launch_bounds__(512, 4) void pair_mfma_k(
    const ushort* __restrict__ se_bf, const ushort* __restrict__ W1simT,
    const int* __restrict__ row_j, const int* __restrict__ row_bucket,
    const float* __restrict__ Ptgt, const float* __restrict__ Pant,
    const float* __restrict__ Pdist, const float* __restrict__ w2,
    float* __restrict__ slow)
{
  __shared__ __align__(16) ushort As[2][128 * 32];   // 16 KB
  __shared__ __align__(16) ushort Bs[2][256 * 32];   // 32 KB
  __shared__ int ks_s[128];
  __shared__ int js_s[128];
  __shared__ int bk_s[128];
  int tid = threadIdx.x;                 // 0..511
  int m0 = blockIdx.x * 128, n0 = blockIdx.y * 256;
  if (tid < 128) {
    int r = m0 + tid;
    ks_s[tid] = r / CC;
    js_s[tid] = row_j[r];
    bk_s[tid] = row_bucket[r];
  }
  __syncthreads();
  int lane = tid & 63, wid = tid >> 6;   // 8 waves
  int quad = lane >> 4, lr = lane & 15;
  int wm = (wid & 1) << 6;               // 0 / 64
  int wn = (wid >> 1) << 6;              // 0 / 64 / 128 / 192
  int ar0 = tid >> 2, aq = tid & 3;      // 128 A-rows, 4 lanes each
  const ushort* pk0 = se_bf + (size_t)ks_s[ar0] * SPAN + aq * 8;
  const ushort* pj0 = se_bf + (size_t)js_s[ar0] * SPAN + aq * 8;
  int gofs[2];
#pragma unroll
  for (int t = 0; t < 2; ++t) {
    int S = t * 512 + tid;               // 0..1023 -> 256 B-rows x 4 slots
    int r = S >> 2, p = S & 3;
    int q = p ^ ((r >> 1) & 3);
    gofs[t] = (n0 + r) * 32 + q * 8;
  }
  // swizzled A-write offset: slot = aq ^ ((row>>1)&3)
  int awi0 = ar0 * 32 + (aq ^ ((ar0 >> 1) & 3)) * 8;

  {
    uint4 ka0 = *(const uint4*)(pk0);
    uint4 ja0 = *(const uint4*)(pj0);
#pragma unroll
    for (int t = 0; t < 2; ++t)
      dma16(W1simT + gofs[t], &Bs[0][(size_t)(t * 512 + tid) * 8]);
    *(uint4*)&As[0][awi0] = pkmul4(ka0, ja0);
  }
  __syncthreads();

  f32x4 acc[4][4] = {};
  for (int k0 = 0; k0 < SPAN; k0 += 32) {
    int buf = (k0 >> 5) & 1, nb = buf ^ 1;
    bool more = (k0 + 32) < SPAN;
    int k1 = more ? k0 + 32 : k0;
    uint4 ka0 = *(const uint4*)(pk0 + k1);
    uint4 ja0 = *(const uint4*)(pj0 + k1);
    if (more) {
      const ushort* sb = W1simT + (size_t)(k1 >> 5) * (NPAD * 32);
#pragma unroll
      for (int t = 0; t < 2; ++t)
        dma16(sb + gofs[t], &Bs[nb][(size_t)(t * 512 + tid) * 8]);
    }
    bf16x8 af[4], bfr[4];
#pragma unroll
    for (int mi = 0; mi < 4; ++mi) {
      int r = wm + mi * 16 + lr;
      int p = quad ^ ((r >> 1) & 3);
      af[mi] = *(const bf16x8*)&As[buf][r * 32 + p * 8];
    }
#pragma unroll
    for (int ni = 0; ni < 4; ++ni) {
      int r = wn + ni * 16 + lr;
      int p = quad ^ ((r >> 1) & 3);
      bfr[ni] = *(const bf16x8*)&Bs[buf][r * 32 + p * 8];
    }
#pragma unroll
    for (int ni = 0; ni < 4; ++ni)
#pragma unroll
      for (int mi = 0; mi < 4; ++mi)
        acc[mi][ni] = __builtin_amdgcn_mfma_f32_16x16x32_bf16(
            af[mi], bfr[ni], acc[mi][ni], 0, 0, 0);
    if (more) {
      *(uint4*)&As[nb][awi0] = pkmul4(ka0, ja0);
    }
    __syncthreads();
  }
  int nn[4]; float w2r[4]; bool nv[4];
#pragma unroll
  for (int ni = 0; ni < 4; ++ni) {
    nn[ni] = n0 + wn + ni * 16 + lr;
    nv[ni] = nn[ni] < HH;
    w2r[ni] = nv[ni] ? w2[nn[ni]] : 0.f;
  }
#pragma unroll
  for (int mi = 0; mi < 4; ++mi) {
#pragma unroll
    for (int reg = 0; reg < 4; ++reg) {
      int rl = wm + mi * 16 + quad * 4 + reg;
      int kk = ks_s[rl], jj = js_s[rl], bb = bk_s[rl];
      float s = 0.f;
#pragma unroll
      for (int ni = 0; ni < 4; ++ni) {
        if (nv[ni]) {
          float h = acc[mi][ni][reg] + Ptgt[(size_t)kk * HH + nn[ni]] +
                    Pant[(size_t)jj * HH + nn[ni]] +
                    Pdist[(size_t)bb * HH + nn[ni]];
          s += fmaxf(h, 0.f) * w2r[ni];
        }
      }
      s += __shfl_xor(s, 1); s += __shfl_xor(s, 2);
      s += __shfl_xor(s, 4); s += __shfl_xor(s, 8);
      if (lr == 0) atomicAdd(&slow[m0 + rl], s);
    }
  }
}

// ---------------------------------------------------------------------------
// K7: finalize (-inf -> -1e30)
// ---------------------------------------------------------------------------
__global__ void finalize_k(const float* __restrict__ slow,
                           const float* __restrict__ top_fast,
                           const float* __restrict__ b2, float* __restrict__ out)
{
  int t = blockIdx.x * 256 + threadIdx.x;
  if (t >= KK * (CC + 1)) return;
  int k = t / (CC + 1), col = t % (CC + 1);
  if (col == 0) {
    out[t] = 0.f;
  } else {
    int r = k * CC + col - 1;
    float v = slow[r] + b2[0] + top_fast[r];
    if (!isfinite(v)) v = -1.0e30f;
    out[t] = v;
  }
}

// ---------------------------------------------------------------------------
extern "C" void kernel_launch(void* const* d_in, const int* in_sizes, int n_in,
                              void* d_out, int out_size, void* d_ws, size_t ws_size,
                              hipStream_t stream)
{
  const float* doc        = (const float*)d_in[0];
  const float* doc1       = (const float*)d_in[1];
  const int*   starts     = (const int*)d_in[2];
  const int*   ends       = (const int*)d_in[3];
  const float* ms         = (const float*)d_in[4];
  const float* attn_w     = (const float*)d_in[5];
  const float* attn_b     = (const float*)d_in[6];
  const float* coarse_w   = (const float*)d_in[7];
  const float* coarse_b   = (const float*)d_in[8];
  const float* dist_prior = (const float*)d_in[9];
  const float* dist_w     = (const float*)d_in[10];
  const float* dist_b     = (const float*)d_in[11];
  const float* top_dist   = (const float*)d_in[12];
  const float* W1         = (const float*)d_in[13];
  const float* b1         = (const float*)d_in[14];
  const float* w2         = (const float*)d_in[15];
  const float* b2         = (const float*)d_in[16];
  float* out = (float*)d_out;

  char* ws = (char*)d_ws;
  size_t off = 0;
  auto alloc = [&](size_t bytes) { void* p = ws + off; off = (off + bytes + 1023) & ~(size_t)1023; return p; };
  float*  hybrid     = (float*)alloc((size_t)WTOK * DD * 4);
  float*  tok_attn   = (float*)alloc((size_t)WTOK * 4);
  ushort* se_bf      = (ushort*)alloc((size_t)KK * SPAN * 2 + 4096);
  ushort* src_bf     = (ushort*)alloc((size_t)KK * SPAN * 2 + 4096);
  float*  fast       = (float*)alloc((size_t)KK * KK * 4);
  float*  Ptgt       = (float*)alloc((size_t)KK * HH * 4);
  float*  Pant       = (float*)alloc((size_t)KK * HH * 4);
  float*  Pdist      = (float*)alloc((size_t)10 * HH * 4);
  float*  dist_score = (float*)alloc(64);
  float*  top_fast   = (float*)alloc((size_t)KK * CC * 4);
  int*    row_j      = (int*)alloc((size_t)KK * CC * 4);
  int*    row_bucket = (int*)alloc((size_t)KK * CC * 4);
  float*  slow       = (float*)alloc((size_t)KK * CC * 4);
  ushort* BigT       = (ushort*)alloc((size_t)NBIG * SPAN * 2 + 4096);   // k-tiled [72][NBIG][32]
  ushort* W1simT     = (ushort*)alloc((size_t)NPAD * SPAN * 2 + 4096);   // k-tiled [72][NPAD][32]
  (void)ws_size; (void)in_sizes; (void)n_in; (void)out_size;

  // 1. fused prep: transposes + dist setup + slow init + hybrid/token-attn
  prep_k<<<PB_TOTAL, 256, 0, stream>>>(coarse_w, W1, dist_prior, dist_w,
                                       dist_b, top_dist, doc, doc1, attn_w,
                                       attn_b, BigT, W1simT, dist_score,
                                       Pdist, slow, hybrid, tok_attn);
  // 2. span embeddings
  span_emb_k<<<KK, 256, 0, stream>>>(doc, hybrid, tok_attn, starts, ends, se_bf);
  // 3. src_bf / Ptgt(+b1) / Pant in one launch (shared A), 64x128 tiles
  {
    dim3 g(KK / 64, NBIG / 128);
    gemm_combined_k<<<g, 256, 0, stream>>>(se_bf, BigT, coarse_b, b1,
                                           src_bf, Ptgt, Pant);
  }
  // 4. fast = src @ se^T with fused epilogue, 64x64 tiles
  {
    dim3 g(KK / 64, KK / 64);
    gemm_fast_k<<<g, 256, 0, stream>>>(src_bf, se_bf, ms, dist_score, fast);
  }
  // 5. top-50
  topk_k<<<KK, 256, 0, stream>>>(fast, top_fast, row_j, row_bucket);
  // 6. fused pair GEMM + epilogue, BM=128 x BN=256, 512 threads,
  //    64x64 wave tiles (x = m fastest within fixed n -> B-panel L2-resident)
  {
    dim3 g((KK * CC) / 128, NPAD / 256);
    pair_mfma_k<<<g, 512, 0, stream>>>(se_bf, W1simT, row_j, row_bucket,
                                       Ptgt, Pant, Pdist, w2, slow);
  }
  // 7. output
  finalize_k<<<(KK * (CC + 1) + 255) / 256, 256, 0, stream>>>(slow, top_fast, b2, out);
}

// Round 8
// 479.259 us; speedup vs baseline: 1.1216x; 1.1066x over previous
//
#include <hip/hip_runtime.h>
#include <math.h>

// W=4096, D=768, K=768, SPAN=3D=2304, F=20, H=1000, PAIR=6932, C=50.
#define WTOK 4096
#define DD   768
#define KK   768
#define SPAN 2304
#define HH   1000
#define CC   50
#define NPAD 1024   // HH padded for pair-GEMM tiles
#define NBIG 4352   // 2304 (coarse) + 1024 (tgt) + 1024 (ant)

typedef __attribute__((ext_vector_type(8))) short bf16x8;
typedef __attribute__((ext_vector_type(4))) float f32x4;
typedef unsigned short ushort;
typedef unsigned int uint;
typedef unsigned long long u64;

__device__ __forceinline__ int bucketd(int d) {
  int l = (d >= 1) ? (31 - __clz(d)) : 0;
  int v = (d <= 4) ? d : (l + 3);
  return min(max(v, 0), 9);
}
__device__ __forceinline__ ushort f2bf(float f) {
  uint u = __float_as_uint(f);
  return (ushort)((u + 0x7fffu + ((u >> 16) & 1u)) >> 16);  // RNE
}
// packed bf16x2 elementwise product, truncating round.
__device__ __forceinline__ uint pkmul_t(uint a, uint b) {
  float lo = __uint_as_float(a << 16) * __uint_as_float(b << 16);
  float hi = __uint_as_float(a & 0xffff0000u) * __uint_as_float(b & 0xffff0000u);
  return __builtin_amdgcn_perm(__float_as_uint(hi), __float_as_uint(lo), 0x07060302u);
}
__device__ __forceinline__ uint4 pkmul4(uint4 a, uint4 b) {
  uint4 r;
  r.x = pkmul_t(a.x, b.x); r.y = pkmul_t(a.y, b.y);
  r.z = pkmul_t(a.z, b.z); r.w = pkmul_t(a.w, b.w);
  return r;
}
// async global->LDS DMA, 16 B per lane
__device__ __forceinline__ void dma16(const ushort* g, ushort* l) {
  __builtin_amdgcn_global_load_lds(
      (const __attribute__((address_space(1))) void*)g,
      (__attribute__((address_space(3))) void*)l, 16, 0, 0);
}
// 64-bit wave shfl_xor via two 32-bit shfls
__device__ __forceinline__ u64 shflx64(u64 v, int msk) {
  uint lo = (uint)v, hi = (uint)(v >> 32);
  lo = (uint)__shfl_xor((int)lo, msk, 64);
  hi = (uint)__shfl_xor((int)hi, msk, 64);
  return ((u64)hi << 32) | lo;
}

// ---------------------------------------------------------------------------
// K0: fused prep: transposes (k-tiled [72][rows][32]), dist setup, slow init,
// + hybrid/token-attn tail
// ---------------------------------------------------------------------------
#define PB_COARSE 5184
#define PB_W 2304
#define PB_SETUP_BASE (PB_COARSE + 3 * PB_W)          // 12096
#define PB_SLOW_BASE  (PB_SETUP_BASE + 40)            // 12136
#define PB_HYB_BASE   (PB_SLOW_BASE + 150)            // 12286
#define PB_TOTAL      (PB_HYB_BASE + WTOK)            // 16382

__global__ __launch_bounds__(256) void prep_k(
    const float* __restrict__ coarse_w, const float* __restrict__ W1,
    const float* __restrict__ dist_prior, const float* __restrict__ dist_w,
    const float* __restrict__ dist_b, const float* __restrict__ top_dist,
    const float* __restrict__ doc, const float* __restrict__ doc1,
    const float* __restrict__ attn_w, const float* __restrict__ attn_b,
    ushort* __restrict__ BigT, ushort* __restrict__ W1simT,
    float* __restrict__ dist_score, float* __restrict__ Pdist,
    float* __restrict__ slow, float* __restrict__ hybrid,
    float* __restrict__ tok_attn)
{
  int bid = blockIdx.x;
  int tid = threadIdx.x;
  if (bid >= PB_HYB_BASE) {
    int w = bid - PB_HYB_BASE;
    float part = 0.f;
    for (int d = tid; d < DD; d += 256) {
      float h = 0.5f * doc[(long)w * DD + d] + 0.5f * doc1[(long)w * DD + d];
      hybrid[(long)w * DD + d] = h;
      part += h * attn_w[d];
    }
    for (int off = 32; off > 0; off >>= 1) part += __shfl_down(part, off, 64);
    __shared__ float ws4[4];
    if ((tid & 63) == 0) ws4[tid >> 6] = part;
    __syncthreads();
    if (tid == 0) tok_attn[w] = ws4[0] + ws4[1] + ws4[2] + ws4[3] + attn_b[0];
    return;
  }
  if (bid >= PB_SLOW_BASE) {
    int t = (bid - PB_SLOW_BASE) * 256 + tid;
    if (t < KK * CC) slow[t] = 0.f;
    return;
  }
  if (bid >= PB_SETUP_BASE) {
    int t = (bid - PB_SETUP_BASE) * 256 + tid;
    if (t < 10) {
      float s = dist_b[0];
      for (int f = 0; f < 20; ++f) s += dist_prior[t * 20 + f] * dist_w[f];
      dist_score[t] = s;
    }
    if (t < 10 * HH) {
      int b = t / HH, h = t % HH;
      float s = 0.f;
      for (int f = 0; f < 20; ++f)
        s += top_dist[b * 20 + f] * W1[(long)(6912 + f) * HH + h];
      Pdist[t] = s;
    }
    return;
  }
  const float* in; int ldin, Cin, nbase, NBrows; ushort* out; int idx;
  int xt;
  if (bid < PB_COARSE) {
    idx = bid; in = coarse_w; ldin = SPAN; Cin = SPAN; nbase = 0;
    NBrows = NBIG; out = BigT; xt = SPAN / 32;
  } else {
    idx = bid - PB_COARSE;
    int region = idx / PB_W;  // 0=tgt 1=ant 2=sim
    idx = idx % PB_W;
    if (region == 0) { in = W1; nbase = 2304; NBrows = NBIG; out = BigT; }
    else if (region == 1) { in = W1 + (size_t)SPAN * HH; nbase = 3328; NBrows = NBIG; out = BigT; }
    else { in = W1 + (size_t)2 * SPAN * HH; nbase = 0; NBrows = NPAD; out = W1simT; }
    ldin = HH; Cin = HH; xt = NPAD / 32;
  }
  {
    int bx = idx % xt, by = idx / xt;
    __shared__ float tile[32][33];
    int n0 = bx * 32, p0 = by * 32;
    int tx = tid & 31, ty = tid >> 5;
    for (int i = ty; i < 32; i += 8) {
      int p = p0 + i, n = n0 + tx;
      tile[i][tx] = (n < Cin) ? in[(long)p * ldin + n] : 0.f;
    }
    __syncthreads();
    size_t slab = (size_t)(p0 >> 5) * NBrows * 32;
    for (int i = ty; i < 32; i += 8) {
      int n = n0 + i;
      out[slab + (size_t)(nbase + n) * 32 + tx] = f2bf(tile[tx][i]);
    }
  }
}

// ---------------------------------------------------------------------------
// K2: span embeddings -> se_bf [KK][SPAN] bf16
// ---------------------------------------------------------------------------
__global__ __launch_bounds__(256) void span_emb_k(
    const float* __restrict__ doc, const float* __restrict__ hybrid,
    const float* __restrict__ tok_attn, const int* __restrict__ starts,
    const int* __restrict__ ends, ushort* __restrict__ se_bf)
{
  int k = blockIdx.x;
  int s = starts[k], e = ends[k];
  int len = e - s + 1;  // <= 30
  int tid = threadIdx.x;
  __shared__ float p_s[32];
  if (tid < 32) {
    float v = (tid < len) ? tok_attn[s + tid] : -INFINITY;
    float m = v;
    for (int msk = 16; msk >= 1; msk >>= 1) m = fmaxf(m, __shfl_xor(m, msk, 32));
    float pe = (tid < len) ? expf(v - m) : 0.f;
    float Z = pe;
    for (int msk = 16; msk >= 1; msk >>= 1) Z += __shfl_xor(Z, msk, 32);
    p_s[tid] = pe / Z;
  }
  __syncthreads();
  for (int d = tid; d < DD; d += 256) {
    float h = 0.f;
    for (int t = 0; t < len; ++t) h += p_s[t] * hybrid[(long)(s + t) * DD + d];
    se_bf[(long)k * SPAN + d]          = f2bf(doc[(long)s * DD + d]);
    se_bf[(long)k * SPAN + DD + d]     = f2bf(doc[(long)e * DD + d]);
    se_bf[(long)k * SPAN + 2 * DD + d] = f2bf(h);
  }
}

// ---------------------------------------------------------------------------
// K3: combined NT GEMM, 64x128 tiles — now DOUBLE-BUFFERED (pair's proven
// 1-barrier pattern): B(k+1) DMA + A(k+1) reg-prefetch issued while
// computing k, so the per-iteration vmcnt(0) drain at the barrier waits on
// loads that had a full compute phase to land (was: staged and drained
// within the same iteration = exposed DMA latency every K-step, 2 barriers).
// ---------------------------------------------------------------------------
__global__ __launch_bounds__(256) void gemm_combined_k(
    const ushort* __restrict__ A, const ushort* __restrict__ B,
    const float* __restrict__ coarse_b, const float* __restrict__ b1,
    ushort* __restrict__ src_bf, float* __restrict__ Ptgt,
    float* __restrict__ Pant)
{
  __shared__ __align__(16) ushort As[2][64 * 40];
  __shared__ __align__(16) ushort Bs[2][128 * 32];
  int tid = threadIdx.x;
  int m0 = blockIdx.x * 64, n0 = blockIdx.y * 128;
  int lane = tid & 63, wid = tid >> 6;
  int quad = lane >> 4, lr = lane & 15;
  int wm = (wid & 1) << 5, wn = (wid >> 1) << 6;
  int arow = tid >> 2, aq = tid & 3;     // A: 64 rows, 4 lanes each
  int gofs[2];
#pragma unroll
  for (int t = 0; t < 2; ++t) {
    int S = t * 256 + tid;
    int r = S >> 2, p = S & 3;
    int q = p ^ ((r >> 1) & 3);
    gofs[t] = (n0 + r) * 32 + q * 8;
  }
  const ushort* ga = A + (size_t)(m0 + arow) * SPAN + aq * 8;
  {
    uint4 a0 = *(const uint4*)(ga);
    dma16(B + gofs[0], &Bs[0][(size_t)(0 * 256 + tid) * 8]);
    dma16(B + gofs[1], &Bs[0][(size_t)(1 * 256 + tid) * 8]);
    *(uint4*)&As[0][arow * 40 + aq * 8] = a0;
  }
  __syncthreads();
  f32x4 acc[2][4] = {};
  for (int k0 = 0; k0 < SPAN; k0 += 32) {
    int buf = (k0 >> 5) & 1, nb = buf ^ 1;
    bool more = (k0 + 32) < SPAN;
    uint4 a_nxt;
    if (more) {
      a_nxt = *(const uint4*)(ga + k0 + 32);
      const ushort* sb = B + (size_t)((k0 >> 5) + 1) * (NBIG * 32);
      dma16(sb + gofs[0], &Bs[nb][(size_t)(0 * 256 + tid) * 8]);
      dma16(sb + gofs[1], &Bs[nb][(size_t)(1 * 256 + tid) * 8]);
    }
    bf16x8 af[2], bfr[4];
#pragma unroll
    for (int mi = 0; mi < 2; ++mi)
      af[mi] = *(const bf16x8*)&As[buf][(wm + mi * 16 + lr) * 40 + quad * 8];
#pragma unroll
    for (int ni = 0; ni < 4; ++ni) {
      int r = wn + ni * 16 + lr;
      int p = quad ^ ((r >> 1) & 3);
      bfr[ni] = *(const bf16x8*)&Bs[buf][r * 32 + p * 8];
    }
#pragma unroll
    for (int mi = 0; mi < 2; ++mi)
#pragma unroll
      for (int ni = 0; ni < 4; ++ni)
        acc[mi][ni] = __builtin_amdgcn_mfma_f32_16x16x32_bf16(
            af[mi], bfr[ni], acc[mi][ni], 0, 0, 0);
    if (more) *(uint4*)&As[nb][arow * 40 + aq * 8] = a_nxt;
    __syncthreads();
  }
#pragma unroll
  for (int mi = 0; mi < 2; ++mi)
#pragma unroll
    for (int ni = 0; ni < 4; ++ni) {
      f32x4 c = acc[mi][ni];
#pragma unroll
      for (int reg = 0; reg < 4; ++reg) {
        int gm = m0 + wm + mi * 16 + quad * 4 + reg;
        int g = n0 + wn + ni * 16 + lr;
        float v = c[reg];
        if (g < 2304) {
          src_bf[(size_t)gm * SPAN + g] = f2bf(v + coarse_b[g]);
        } else if (g < 3328) {
          int n = g - 2304;
          if (n < HH) Ptgt[(size_t)gm * HH + n] = v + b1[n];  // b1 folded in
        } else {
          int n = g - 3328;
          if (n < HH) Pant[(size_t)gm * HH + n] = v;
        }
      }
    }
}

// ---------------------------------------------------------------------------
// K4: fast GEMM (src @ se^T), 64x64 tiles — double-buffered, 1 barrier/iter
// (was 2 barriers + same-iteration staging).
// ---------------------------------------------------------------------------
__global__ __launch_bounds__(256) void gemm_fast_k(
    const ushort* __restrict__ A, const ushort* __restrict__ B,
    const float* __restrict__ ms, const float* __restrict__ dist_score,
    float* __restrict__ fast)
{
  __shared__ __align__(16) ushort As[2][64 * 40];
  __shared__ __align__(16) ushort Bs[2][64 * 40];
  int tid = threadIdx.x;
  int m0 = blockIdx.x * 64, n0 = blockIdx.y * 64;
  int lane = tid & 63, wid = tid >> 6;
  int quad = lane >> 4, lr = lane & 15;
  int wm = (wid & 1) << 5, wn = (wid >> 1) << 5;
  int row = tid >> 2, aq = tid & 3;
  const ushort* ga = A + (size_t)(m0 + row) * SPAN + aq * 8;
  const ushort* gb = B + (size_t)(n0 + row) * SPAN + aq * 8;
  {
    uint4 a0 = *(const uint4*)(ga);
    uint4 b0 = *(const uint4*)(gb);
    *(uint4*)&As[0][row * 40 + aq * 8] = a0;
    *(uint4*)&Bs[0][row * 40 + aq * 8] = b0;
  }
  __syncthreads();
  f32x4 acc[2][2] = {};
  for (int k0 = 0; k0 < SPAN; k0 += 32) {
    int buf = (k0 >> 5) & 1, nb = buf ^ 1;
    bool more = (k0 + 32) < SPAN;
    uint4 a_nxt, b_nxt;
    if (more) {
      a_nxt = *(const uint4*)(ga + k0 + 32);
      b_nxt = *(const uint4*)(gb + k0 + 32);
    }
    bf16x8 af[2], bfr[2];
#pragma unroll
    for (int mi = 0; mi < 2; ++mi)
      af[mi] = *(const bf16x8*)&As[buf][(wm + mi * 16 + lr) * 40 + quad * 8];
#pragma unroll
    for (int ni = 0; ni < 2; ++ni)
      bfr[ni] = *(const bf16x8*)&Bs[buf][(wn + ni * 16 + lr) * 40 + quad * 8];
#pragma unroll
    for (int mi = 0; mi < 2; ++mi)
#pragma unroll
      for (int ni = 0; ni < 2; ++ni)
        acc[mi][ni] = __builtin_amdgcn_mfma_f32_16x16x32_bf16(
            af[mi], bfr[ni], acc[mi][ni], 0, 0, 0);
    if (more) {
      *(uint4*)&As[nb][row * 40 + aq * 8] = a_nxt;
      *(uint4*)&Bs[nb][row * 40 + aq * 8] = b_nxt;
    }
    __syncthreads();
  }
#pragma unroll
  for (int mi = 0; mi < 2; ++mi)
#pragma unroll
    for (int ni = 0; ni < 2; ++ni) {
      f32x4 c = acc[mi][ni];
#pragma unroll
      for (int reg = 0; reg < 4; ++reg) {
        int gm = m0 + wm + mi * 16 + quad * 4 + reg;
        int gn = n0 + wn + ni * 16 + lr;
        float v;
        if (gn < gm) {
          v = c[reg] + ms[gm] + ms[gn] + dist_score[bucketd(gm - gn)];
        } else {
          v = -INFINITY;
        }
        fast[(size_t)gm * KK + gn] = v;
      }
    }
}

// ---------------------------------------------------------------------------
// K5: exact top-50 — ZERO-BARRIER wave-per-row rewrite (was 50 iterations x
// 2 __syncthreads + serial tid0 merge). Each row's 768 values live in
// registers as unique 64-bit keys: (sortable_float << 10) | (1023 - j).
// Key order == (value desc, index asc) == lax.top_k tie rule. 50 extractions
// of wave-max (6 shfl_xor), owner lane zeroes its copy, lane 0 reconstructs
// the bit-exact float from the key. No LDS, no barriers.
// ---------------------------------------------------------------------------
__global__ __launch_bounds__(256) void topk_k(
    const float* __restrict__ fast, float* __restrict__ top_fast,
    int* __restrict__ row_j, int* __restrict__ row_bucket)
{
  int lane = threadIdx.x & 63;
  int k = blockIdx.x * 4 + (threadIdx.x >> 6);   // one wave per row
  u64 key[12];
#pragma unroll
  for (int i = 0; i < 12; ++i) {
    int j = lane + i * 64;
    uint u = __float_as_uint(fast[(size_t)k * KK + j]);
    uint s = (u & 0x80000000u) ? ~u : (u | 0x80000000u);
    key[i] = ((u64)s << 10) | (u64)(1023 - j);
  }
  for (int it = 0; it < CC; ++it) {
    u64 gm = key[0];
#pragma unroll
    for (int i = 1; i < 12; ++i) gm = (key[i] > gm) ? key[i] : gm;
    for (int msk = 32; msk > 0; msk >>= 1) {
      u64 o = shflx64(gm, msk);
      gm = (o > gm) ? o : gm;
    }
#pragma unroll
    for (int i = 0; i < 12; ++i) if (key[i] == gm) key[i] = 0;
    if (lane == 0) {
      uint s = (uint)(gm >> 10);
      uint u = (s & 0x80000000u) ? (s & 0x7fffffffu) : ~s;
      int j = 1023 - (int)(gm & 1023u);
      int r = k * CC + it;
      top_fast[r] = __uint_as_float(u);
      row_j[r] = j;
      row_bucket[r] = bucketd(k - j);
    }
  }
}

// ---------------------------------------------------------------------------
// K6: pair GEMM — exact R5 config (best measured: 240 µs). BM=128 x BN=256,
// 512 thr, 8 waves as 4m(32) x 2n(128), dbuf, 1 barrier/iter, LDS 49.5 KB,
// unpadded XOR-swizzled A and B (0 bank conflicts), pkmul via v_perm_b32.
// ---------------------------------------------------------------------------
__global__ __launch_bounds__(512, 4) void pair_mfma_k(
    const ushort* __restrict__ se_bf, const ushort* __restrict__ W1simT,
    const int* __restrict__ row_j, const int* __restrict__ row_bucket,
    const float* __restrict__ Ptgt, const float* __restrict__ Pant,
    const float* __restrict__ Pdist, const float* __restrict__ w2,
    float* __restrict__ slow)
{
  __shared__ __align__(16) ushort As[2][128 * 32];   // 16 KB
  __shared__ __align__(16) ushort Bs[2][256 * 32];   // 32 KB
  __shared__ int ks_s[128];
  __shared__ int js_s[128];
  __shared__ int bk_s[128];
  int tid = threadIdx.x;                 // 0..511
  int m0 = blockIdx.x * 128, n0 = blockIdx.y * 256;
  if (tid < 128) {
    int r = m0 + tid;
    ks_s[tid] = r / CC;
    js_s[tid] = row_j[r];
    bk_s[tid] = row_bucket[r];
  }
  __syncthreads();
  int lane = tid & 63, wid = tid >> 6;   // 8 waves
  int quad = lane >> 4, lr = lane & 15;
  int wm = (wid & 3) << 5;               // 0,32,64,96
  int wn = (wid >> 2) << 7;              // 0,128
  int ar0 = tid >> 2, aq = tid & 3;      // 128 A-rows, 4 lanes each
  const ushort* pk0 = se_bf + (size_t)ks_s[ar0] * SPAN + aq * 8;
  const ushort* pj0 = se_bf + (size_t)js_s[ar0] * SPAN + aq * 8;
  int gofs[2];
#pragma unroll
  for (int t = 0; t < 2; ++t) {
    int S = t * 512 + tid;               // 0..1023 -> 256 B-rows x 4 slots
    int r = S >> 2, p = S & 3;
    int q = p ^ ((r >> 1) & 3);
    gofs[t] = (n0 + r) * 32 + q * 8;
  }
  int awi0 = ar0 * 32 + (aq ^ ((ar0 >> 1) & 3)) * 8;

  {
    uint4 ka0 = *(const uint4*)(pk0);
    uint4 ja0 = *(const uint4*)(pj0);
#pragma unroll
    for (int t = 0; t < 2; ++t)
      dma16(W1simT + gofs[t], &Bs[0][(size_t)(t * 512 + tid) * 8]);
    *(uint4*)&As[0][awi0] = pkmul4(ka0, ja0);
  }
  __syncthreads();

  f32x4 acc[2][8] = {};
  for (int k0 = 0; k0 < SPAN; k0 += 32) {
    int buf = (k0 >> 5) & 1, nb = buf ^ 1;
    bool more = (k0 + 32) < SPAN;
    int k1 = more ? k0 + 32 : k0;
    uint4 ka0 = *(const uint4*)(pk0 + k1);
    uint4 ja0 = *(const uint4*)(pj0 + k1);
    if (more) {
      const ushort* sb = W1simT + (size_t)(k1 >> 5) * (NPAD * 32);
#pragma unroll
      for (int t = 0; t < 2; ++t)
        dma16(sb + gofs[t], &Bs[nb][(size_t)(t * 512 + tid) * 8]);
    }
    bf16x8 af[2], bfr[8];
#pragma unroll
    for (int mi = 0; mi < 2; ++mi) {
      int r = wm + mi * 16 + lr;
      int p = quad ^ ((r >> 1) & 3);
      af[mi] = *(const bf16x8*)&As[buf][r * 32 + p * 8];
    }
#pragma unroll
    for (int ni = 0; ni < 8; ++ni) {
      int r = wn + ni * 16 + lr;
      int p = quad ^ ((r >> 1) & 3);
      bfr[ni] = *(const bf16x8*)&Bs[buf][r * 32 + p * 8];
    }
#pragma unroll
    for (int ni = 0; ni < 8; ++ni)
#pragma unroll
      for (int mi = 0; mi < 2; ++mi)
        acc[mi][ni] = __builtin_amdgcn_mfma_f32_16x16x32_bf16(
            af[mi], bfr[ni], acc[mi][ni], 0, 0, 0);
    if (more) {
      *(uint4*)&As[nb][awi0] = pkmul4(ka0, ja0);
    }
    __syncthreads();
  }
  int nn[8]; float w2r[8]; bool nv[8];
#pragma unroll
  for (int ni = 0; ni < 8; ++ni) {
    nn[ni] = n0 + wn + ni * 16 + lr;
    nv[ni] = nn[ni] < HH;
    w2r[ni] = nv[ni] ? w2[nn[ni]] : 0.f;
  }
#pragma unroll
  for (int mi = 0; mi < 2; ++mi) {
#pragma unroll
    for (int reg = 0; reg < 4; ++reg) {
      int rl = wm + mi * 16 + quad * 4 + reg;
      int kk = ks_s[rl], jj = js_s[rl], bb = bk_s[rl];
      float s = 0.f;
#pragma unroll
      for (int ni = 0; ni < 8; ++ni) {
        if (nv[ni]) {
          float h = acc[mi][ni][reg] + Ptgt[(size_t)kk * HH + nn[ni]] +
                    Pant[(size_t)jj * HH + nn[ni]] +
                    Pdist[(size_t)bb * HH + nn[ni]];
          s += fmaxf(h, 0.f) * w2r[ni];
        }
      }
      s += __shfl_xor(s, 1); s += __shfl_xor(s, 2);
      s += __shfl_xor(s, 4); s += __shfl_xor(s, 8);
      if (lr == 0) atomicAdd(&slow[m0 + rl], s);
    }
  }
}

// ---------------------------------------------------------------------------
// K7: finalize (-inf -> -1e30)
// ---------------------------------------------------------------------------
__global__ void finalize_k(const float* __restrict__ slow,
                           const float* __restrict__ top_fast,
                           const float* __restrict__ b2, float* __restrict__ out)
{
  int t = blockIdx.x * 256 + threadIdx.x;
  if (t >= KK * (CC + 1)) return;
  int k = t / (CC + 1), col = t % (CC + 1);
  if (col == 0) {
    out[t] = 0.f;
  } else {
    int r = k * CC + col - 1;
    float v = slow[r] + b2[0] + top_fast[r];
    if (!isfinite(v)) v = -1.0e30f;
    out[t] = v;
  }
}

// ---------------------------------------------------------------------------
extern "C" void kernel_launch(void* const* d_in, const int* in_sizes, int n_in,
                              void* d_out, int out_size, void* d_ws, size_t ws_size,
                              hipStream_t stream)
{
  const float* doc        = (const float*)d_in[0];
  const float* doc1       = (const float*)d_in[1];
  const int*   starts     = (const int*)d_in[2];
  const int*   ends       = (const int*)d_in[3];
  const float* ms         = (const float*)d_in[4];
  const float* attn_w     = (const float*)d_in[5];
  const float* attn_b     = (const float*)d_in[6];
  const float* coarse_w   = (const float*)d_in[7];
  const float* coarse_b   = (const float*)d_in[8];
  const float* dist_prior = (const float*)d_in[9];
  const float* dist_w     = (const float*)d_in[10];
  const float* dist_b     = (const float*)d_in[11];
  const float* top_dist   = (const float*)d_in[12];
  const float* W1         = (const float*)d_in[13];
  const float* b1         = (const float*)d_in[14];
  const float* w2         = (const float*)d_in[15];
  const float* b2         = (const float*)d_in[16];
  float* out = (float*)d_out;

  char* ws = (char*)d_ws;
  size_t off = 0;
  auto alloc = [&](size_t bytes) { void* p = ws + off; off = (off + bytes + 1023) & ~(size_t)1023; return p; };
  float*  hybrid     = (float*)alloc((size_t)WTOK * DD * 4);
  float*  tok_attn   = (float*)alloc((size_t)WTOK * 4);
  ushort* se_bf      = (ushort*)alloc((size_t)KK * SPAN * 2 + 4096);
  ushort* src_bf     = (ushort*)alloc((size_t)KK * SPAN * 2 + 4096);
  float*  fast       = (float*)alloc((size_t)KK * KK * 4);
  float*  Ptgt       = (float*)alloc((size_t)KK * HH * 4);
  float*  Pant       = (float*)alloc((size_t)KK * HH * 4);
  float*  Pdist      = (float*)alloc((size_t)10 * HH * 4);
  float*  dist_score = (float*)alloc(64);
  float*  top_fast   = (float*)alloc((size_t)KK * CC * 4);
  int*    row_j      = (int*)alloc((size_t)KK * CC * 4);
  int*    row_bucket = (int*)alloc((size_t)KK * CC * 4);
  float*  slow       = (float*)alloc((size_t)KK * CC * 4);
  ushort* BigT       = (ushort*)alloc((size_t)NBIG * SPAN * 2 + 4096);   // k-tiled [72][NBIG][32]
  ushort* W1simT     = (ushort*)alloc((size_t)NPAD * SPAN * 2 + 4096);   // k-tiled [72][NPAD][32]
  (void)ws_size; (void)in_sizes; (void)n_in; (void)out_size;

  // 1. fused prep: transposes + dist setup + slow init + hybrid/token-attn
  prep_k<<<PB_TOTAL, 256, 0, stream>>>(coarse_w, W1, dist_prior, dist_w,
                                       dist_b, top_dist, doc, doc1, attn_w,
                                       attn_b, BigT, W1simT, dist_score,
                                       Pdist, slow, hybrid, tok_attn);
  // 2. span embeddings
  span_emb_k<<<KK, 256, 0, stream>>>(doc, hybrid, tok_attn, starts, ends, se_bf);
  // 3. src_bf / Ptgt(+b1) / Pant in one launch (shared A), 64x128 tiles, dbuf
  {
    dim3 g(KK / 64, NBIG / 128);
    gemm_combined_k<<<g, 256, 0, stream>>>(se_bf, BigT, coarse_b, b1,
                                           src_bf, Ptgt, Pant);
  }
  // 4. fast = src @ se^T with fused epilogue, 64x64 tiles, dbuf
  {
    dim3 g(KK / 64, KK / 64);
    gemm_fast_k<<<g, 256, 0, stream>>>(src_bf, se_bf, ms, dist_score, fast);
  }
  // 5. top-50, wave-per-row, zero barriers
  topk_k<<<KK / 4, 256, 0, stream>>>(fast, top_fast, row_j, row_bucket);
  // 6. fused pair GEMM + epilogue, R5 config (BM=128 x BN=256, 512 thr)
  {
    dim3 g((KK * CC) / 128, NPAD / 256);
    pair_mfma_k<<<g, 512, 0, stream>>>(se_bf, W1simT, row_j, row_bucket,
                                       Ptgt, Pant, Pdist, w2, slow);
  }
  // 7. output
  finalize_k<<<(KK * (CC + 1) + 255) / 256, 256, 0, stream>>>(slow, top_fast, b2, out);
}

// Round 9
// 476.923 us; speedup vs baseline: 1.1271x; 1.0049x over previous
//
#include <hip/hip_runtime.h>
#include <math.h>

// W=4096, D=768, K=768, SPAN=3D=2304, F=20, H=1000, PAIR=6932, C=50.
#define WTOK 4096
#define DD   768
#define KK   768
#define SPAN 2304
#define HH   1000
#define CC   50
#define NPAD 1024   // HH padded for pair-GEMM tiles
#define NBIG 4352   // 2304 (coarse) + 1024 (tgt) + 1024 (ant)

typedef __attribute__((ext_vector_type(8))) short bf16x8;
typedef __attribute__((ext_vector_type(4))) float f32x4;
typedef unsigned short ushort;
typedef unsigned int uint;
typedef unsigned long long u64;

__device__ __forceinline__ int bucketd(int d) {
  int l = (d >= 1) ? (31 - __clz(d)) : 0;
  int v = (d <= 4) ? d : (l + 3);
  return min(max(v, 0), 9);
}
__device__ __forceinline__ ushort f2bf(float f) {
  uint u = __float_as_uint(f);
  return (ushort)((u + 0x7fffu + ((u >> 16) & 1u)) >> 16);  // RNE
}
// packed bf16x2 elementwise product, truncating round.
__device__ __forceinline__ uint pkmul_t(uint a, uint b) {
  float lo = __uint_as_float(a << 16) * __uint_as_float(b << 16);
  float hi = __uint_as_float(a & 0xffff0000u) * __uint_as_float(b & 0xffff0000u);
  return __builtin_amdgcn_perm(__float_as_uint(hi), __float_as_uint(lo), 0x07060302u);
}
__device__ __forceinline__ uint4 pkmul4(uint4 a, uint4 b) {
  uint4 r;
  r.x = pkmul_t(a.x, b.x); r.y = pkmul_t(a.y, b.y);
  r.z = pkmul_t(a.z, b.z); r.w = pkmul_t(a.w, b.w);
  return r;
}
// async global->LDS DMA, 16 B per lane
__device__ __forceinline__ void dma16(const ushort* g, ushort* l) {
  __builtin_amdgcn_global_load_lds(
      (const __attribute__((address_space(1))) void*)g,
      (__attribute__((address_space(3))) void*)l, 16, 0, 0);
}
// 64-bit wave shfl_xor via two 32-bit shfls
__device__ __forceinline__ u64 shflx64(u64 v, int msk) {
  uint lo = (uint)v, hi = (uint)(v >> 32);
  lo = (uint)__shfl_xor((int)lo, msk, 64);
  hi = (uint)__shfl_xor((int)hi, msk, 64);
  return ((u64)hi << 32) | lo;
}

// ---------------------------------------------------------------------------
// K0: fused prep: transposes (k-tiled [72][rows][32], now 64x64 tiles ->
// 3024 blocks instead of 12096: less dispatch raggedness), dist setup,
// slow init, hybrid/token-attn tail.
// ---------------------------------------------------------------------------
#define PB_COARSE 1296                                 // (2304/64)^2
#define PB_W 576                                       // (1024/64)*(2304/64)
#define PB_SETUP_BASE (PB_COARSE + 3 * PB_W)          // 3024
#define PB_SLOW_BASE  (PB_SETUP_BASE + 40)            // 3064
#define PB_HYB_BASE   (PB_SLOW_BASE + 150)            // 3214
#define PB_TOTAL      (PB_HYB_BASE + WTOK)            // 7310

__global__ __launch_bounds__(256) void prep_k(
    const float* __restrict__ coarse_w, const float* __restrict__ W1,
    const float* __restrict__ dist_prior, const float* __restrict__ dist_w,
    const float* __restrict__ dist_b, const float* __restrict__ top_dist,
    const float* __restrict__ doc, const float* __restrict__ doc1,
    const float* __restrict__ attn_w, const float* __restrict__ attn_b,
    ushort* __restrict__ BigT, ushort* __restrict__ W1simT,
    float* __restrict__ dist_score, float* __restrict__ Pdist,
    float* __restrict__ slow, float* __restrict__ hybrid,
    float* __restrict__ tok_attn)
{
  int bid = blockIdx.x;
  int tid = threadIdx.x;
  if (bid >= PB_HYB_BASE) {
    int w = bid - PB_HYB_BASE;
    float part = 0.f;
    for (int d = tid; d < DD; d += 256) {
      float h = 0.5f * doc[(long)w * DD + d] + 0.5f * doc1[(long)w * DD + d];
      hybrid[(long)w * DD + d] = h;
      part += h * attn_w[d];
    }
    for (int off = 32; off > 0; off >>= 1) part += __shfl_down(part, off, 64);
    __shared__ float ws4[4];
    if ((tid & 63) == 0) ws4[tid >> 6] = part;
    __syncthreads();
    if (tid == 0) tok_attn[w] = ws4[0] + ws4[1] + ws4[2] + ws4[3] + attn_b[0];
    return;
  }
  if (bid >= PB_SLOW_BASE) {
    int t = (bid - PB_SLOW_BASE) * 256 + tid;
    if (t < KK * CC) slow[t] = 0.f;
    return;
  }
  if (bid >= PB_SETUP_BASE) {
    int t = (bid - PB_SETUP_BASE) * 256 + tid;
    if (t < 10) {
      float s = dist_b[0];
      for (int f = 0; f < 20; ++f) s += dist_prior[t * 20 + f] * dist_w[f];
      dist_score[t] = s;
    }
    if (t < 10 * HH) {
      int b = t / HH, h = t % HH;
      float s = 0.f;
      for (int f = 0; f < 20; ++f)
        s += top_dist[b * 20 + f] * W1[(long)(6912 + f) * HH + h];
      Pdist[t] = s;
    }
    return;
  }
  const float* in; int ldin, Cin, nbase, NBrows; ushort* out; int idx;
  int xt;
  if (bid < PB_COARSE) {
    idx = bid; in = coarse_w; ldin = SPAN; Cin = SPAN; nbase = 0;
    NBrows = NBIG; out = BigT; xt = SPAN / 64;
  } else {
    idx = bid - PB_COARSE;
    int region = idx / PB_W;  // 0=tgt 1=ant 2=sim
    idx = idx % PB_W;
    if (region == 0) { in = W1; nbase = 2304; NBrows = NBIG; out = BigT; }
    else if (region == 1) { in = W1 + (size_t)SPAN * HH; nbase = 3328; NBrows = NBIG; out = BigT; }
    else { in = W1 + (size_t)2 * SPAN * HH; nbase = 0; NBrows = NPAD; out = W1simT; }
    ldin = HH; Cin = HH; xt = NPAD / 64;
  }
  {
    int bx = idx % xt, by = idx / xt;
    __shared__ float tile[64][65];
    int n0 = bx * 64, p0 = by * 64;
    int tx = tid & 63, ty = tid >> 6;   // 4 rows per iter
    for (int i = ty; i < 64; i += 4) {
      int p = p0 + i, n = n0 + tx;
      tile[i][tx] = (n < Cin) ? in[(long)p * ldin + n] : 0.f;
    }
    __syncthreads();
    // p0 is a multiple of 64 -> tx spans 2 k-chunks
    size_t obase = (size_t)(((p0 + tx) >> 5)) * NBrows * 32 + (tx & 31);
    for (int i = ty; i < 64; i += 4) {
      int n = n0 + i;
      out[obase + (size_t)(nbase + n) * 32] = f2bf(tile[tx][i]);
    }
  }
}

// ---------------------------------------------------------------------------
// K2: span embeddings -> se_bf [KK][SPAN] bf16
// ---------------------------------------------------------------------------
__global__ __launch_bounds__(256) void span_emb_k(
    const float* __restrict__ doc, const float* __restrict__ hybrid,
    const float* __restrict__ tok_attn, const int* __restrict__ starts,
    const int* __restrict__ ends, ushort* __restrict__ se_bf)
{
  int k = blockIdx.x;
  int s = starts[k], e = ends[k];
  int len = e - s + 1;  // <= 30
  int tid = threadIdx.x;
  __shared__ float p_s[32];
  if (tid < 32) {
    float v = (tid < len) ? tok_attn[s + tid] : -INFINITY;
    float m = v;
    for (int msk = 16; msk >= 1; msk >>= 1) m = fmaxf(m, __shfl_xor(m, msk, 32));
    float pe = (tid < len) ? expf(v - m) : 0.f;
    float Z = pe;
    for (int msk = 16; msk >= 1; msk >>= 1) Z += __shfl_xor(Z, msk, 32);
    p_s[tid] = pe / Z;
  }
  __syncthreads();
  for (int d = tid; d < DD; d += 256) {
    float h = 0.f;
    for (int t = 0; t < len; ++t) h += p_s[t] * hybrid[(long)(s + t) * DD + d];
    se_bf[(long)k * SPAN + d]          = f2bf(doc[(long)s * DD + d]);
    se_bf[(long)k * SPAN + DD + d]     = f2bf(doc[(long)e * DD + d]);
    se_bf[(long)k * SPAN + 2 * DD + d] = f2bf(h);
  }
}

// ---------------------------------------------------------------------------
// K3: combined NT GEMM, 64x128 tiles — dbuf + BK=64 (36 K-steps, half the
// barrier/drain fixed costs). kh-ordered MFMA preserves the exact per-acc
// k-sequence -> bit-identical to BK=32.
// ---------------------------------------------------------------------------
__global__ __launch_bounds__(256) void gemm_combined_k(
    const ushort* __restrict__ A, const ushort* __restrict__ B,
    const float* __restrict__ coarse_b, const float* __restrict__ b1,
    ushort* __restrict__ src_bf, float* __restrict__ Ptgt,
    float* __restrict__ Pant)
{
  __shared__ __align__(16) ushort As[2][64 * 72];      // 18.4 KB
  __shared__ __align__(16) ushort Bs[2][2][128 * 32];  // 32 KB
  int tid = threadIdx.x;
  int m0 = blockIdx.x * 64, n0 = blockIdx.y * 128;
  int lane = tid & 63, wid = tid >> 6;
  int quad = lane >> 4, lr = lane & 15;
  int wm = (wid & 1) << 5, wn = (wid >> 1) << 6;
  int arow = tid >> 2, aq = tid & 3;     // A: 64 rows, 4 lanes each
  int gofs[2];
#pragma unroll
  for (int t = 0; t < 2; ++t) {
    int S = t * 256 + tid;
    int r = S >> 2, p = S & 3;
    int q = p ^ ((r >> 1) & 3);
    gofs[t] = (n0 + r) * 32 + q * 8;
  }
  const ushort* ga = A + (size_t)(m0 + arow) * SPAN + aq * 8;
  {
    uint4 alo = *(const uint4*)(ga);
    uint4 ahi = *(const uint4*)(ga + 32);
#pragma unroll
    for (int kh = 0; kh < 2; ++kh)
#pragma unroll
      for (int t = 0; t < 2; ++t)
        dma16(B + (size_t)kh * (NBIG * 32) + gofs[t],
              &Bs[0][kh][(size_t)(t * 256 + tid) * 8]);
    *(uint4*)&As[0][arow * 72 + aq * 8] = alo;
    *(uint4*)&As[0][arow * 72 + 32 + aq * 8] = ahi;
  }
  __syncthreads();
  f32x4 acc[2][4] = {};
  for (int s = 0; s < 36; ++s) {
    int buf = s & 1, nb = buf ^ 1;
    bool more = (s + 1) < 36;
    uint4 alo, ahi;
    if (more) {
      alo = *(const uint4*)(ga + (s + 1) * 64);
      ahi = *(const uint4*)(ga + (s + 1) * 64 + 32);
#pragma unroll
      for (int kh = 0; kh < 2; ++kh)
#pragma unroll
        for (int t = 0; t < 2; ++t)
          dma16(B + (size_t)(2 * (s + 1) + kh) * (NBIG * 32) + gofs[t],
                &Bs[nb][kh][(size_t)(t * 256 + tid) * 8]);
    }
    bf16x8 af[2][2], bfr[4][2];
#pragma unroll
    for (int mi = 0; mi < 2; ++mi)
#pragma unroll
      for (int kh = 0; kh < 2; ++kh)
        af[mi][kh] = *(const bf16x8*)&As[buf][(wm + mi * 16 + lr) * 72 + kh * 32 + quad * 8];
#pragma unroll
    for (int ni = 0; ni < 4; ++ni) {
      int r = wn + ni * 16 + lr;
      int p = quad ^ ((r >> 1) & 3);
#pragma unroll
      for (int kh = 0; kh < 2; ++kh)
        bfr[ni][kh] = *(const bf16x8*)&Bs[buf][kh][r * 32 + p * 8];
    }
#pragma unroll
    for (int kh = 0; kh < 2; ++kh)
#pragma unroll
      for (int mi = 0; mi < 2; ++mi)
#pragma unroll
        for (int ni = 0; ni < 4; ++ni)
          acc[mi][ni] = __builtin_amdgcn_mfma_f32_16x16x32_bf16(
              af[mi][kh], bfr[ni][kh], acc[mi][ni], 0, 0, 0);
    if (more) {
      *(uint4*)&As[nb][arow * 72 + aq * 8] = alo;
      *(uint4*)&As[nb][arow * 72 + 32 + aq * 8] = ahi;
    }
    __syncthreads();
  }
#pragma unroll
  for (int mi = 0; mi < 2; ++mi)
#pragma unroll
    for (int ni = 0; ni < 4; ++ni) {
      f32x4 c = acc[mi][ni];
#pragma unroll
      for (int reg = 0; reg < 4; ++reg) {
        int gm = m0 + wm + mi * 16 + quad * 4 + reg;
        int g = n0 + wn + ni * 16 + lr;
        float v = c[reg];
        if (g < 2304) {
          src_bf[(size_t)gm * SPAN + g] = f2bf(v + coarse_b[g]);
        } else if (g < 3328) {
          int n = g - 2304;
          if (n < HH) Ptgt[(size_t)gm * HH + n] = v + b1[n];  // b1 folded in
        } else {
          int n = g - 3328;
          if (n < HH) Pant[(size_t)gm * HH + n] = v;
        }
      }
    }
}

// ---------------------------------------------------------------------------
// K4: fast GEMM (src @ se^T), 64x64 tiles — dbuf + BK=64 (36 steps; this
// kernel is 144 blocks = one critical path, so halving barriers acts
// directly on wall time).
// ---------------------------------------------------------------------------
__global__ __launch_bounds__(256) void gemm_fast_k(
    const ushort* __restrict__ A, const ushort* __restrict__ B,
    const float* __restrict__ ms, const float* __restrict__ dist_score,
    float* __restrict__ fast)
{
  __shared__ __align__(16) ushort As[2][64 * 72];
  __shared__ __align__(16) ushort Bs[2][64 * 72];
  int tid = threadIdx.x;
  int m0 = blockIdx.x * 64, n0 = blockIdx.y * 64;
  int lane = tid & 63, wid = tid >> 6;
  int quad = lane >> 4, lr = lane & 15;
  int wm = (wid & 1) << 5, wn = (wid >> 1) << 5;
  int row = tid >> 2, aq = tid & 3;
  const ushort* ga = A + (size_t)(m0 + row) * SPAN + aq * 8;
  const ushort* gb = B + (size_t)(n0 + row) * SPAN + aq * 8;
  {
    uint4 a0 = *(const uint4*)(ga);
    uint4 a1 = *(const uint4*)(ga + 32);
    uint4 b0 = *(const uint4*)(gb);
    uint4 b1v = *(const uint4*)(gb + 32);
    *(uint4*)&As[0][row * 72 + aq * 8] = a0;
    *(uint4*)&As[0][row * 72 + 32 + aq * 8] = a1;
    *(uint4*)&Bs[0][row * 72 + aq * 8] = b0;
    *(uint4*)&Bs[0][row * 72 + 32 + aq * 8] = b1v;
  }
  __syncthreads();
  f32x4 acc[2][2] = {};
  for (int s = 0; s < 36; ++s) {
    int buf = s & 1, nb = buf ^ 1;
    bool more = (s + 1) < 36;
    uint4 a0, a1, b0, b1v;
    if (more) {
      a0 = *(const uint4*)(ga + (s + 1) * 64);
      a1 = *(const uint4*)(ga + (s + 1) * 64 + 32);
      b0 = *(const uint4*)(gb + (s + 1) * 64);
      b1v = *(const uint4*)(gb + (s + 1) * 64 + 32);
    }
    bf16x8 af[2][2], bfr[2][2];
#pragma unroll
    for (int mi = 0; mi < 2; ++mi)
#pragma unroll
      for (int kh = 0; kh < 2; ++kh)
        af[mi][kh] = *(const bf16x8*)&As[buf][(wm + mi * 16 + lr) * 72 + kh * 32 + quad * 8];
#pragma unroll
    for (int ni = 0; ni < 2; ++ni)
#pragma unroll
      for (int kh = 0; kh < 2; ++kh)
        bfr[ni][kh] = *(const bf16x8*)&Bs[buf][(wn + ni * 16 + lr) * 72 + kh * 32 + quad * 8];
#pragma unroll
    for (int kh = 0; kh < 2; ++kh)
#pragma unroll
      for (int mi = 0; mi < 2; ++mi)
#pragma unroll
        for (int ni = 0; ni < 2; ++ni)
          acc[mi][ni] = __builtin_amdgcn_mfma_f32_16x16x32_bf16(
              af[mi][kh], bfr[ni][kh], acc[mi][ni], 0, 0, 0);
    if (more) {
      *(uint4*)&As[nb][row * 72 + aq * 8] = a0;
      *(uint4*)&As[nb][row * 72 + 32 + aq * 8] = a1;
      *(uint4*)&Bs[nb][row * 72 + aq * 8] = b0;
      *(uint4*)&Bs[nb][row * 72 + 32 + aq * 8] = b1v;
    }
    __syncthreads();
  }
#pragma unroll
  for (int mi = 0; mi < 2; ++mi)
#pragma unroll
    for (int ni = 0; ni < 2; ++ni) {
      f32x4 c = acc[mi][ni];
#pragma unroll
      for (int reg = 0; reg < 4; ++reg) {
        int gm = m0 + wm + mi * 16 + quad * 4 + reg;
        int gn = n0 + wn + ni * 16 + lr;
        float v;
        if (gn < gm) {
          v = c[reg] + ms[gm] + ms[gn] + dist_score[bucketd(gm - gn)];
        } else {
          v = -INFINITY;
        }
        fast[(size_t)gm * KK + gn] = v;
      }
    }
}

// ---------------------------------------------------------------------------
// K5: exact top-50 — zero-barrier wave-per-row (R8, proven). Keys
// (sortable_float << 10) | (1023 - j): order == (value desc, index asc).
// ---------------------------------------------------------------------------
__global__ __launch_bounds__(256) void topk_k(
    const float* __restrict__ fast, float* __restrict__ top_fast,
    int* __restrict__ row_j, int* __restrict__ row_bucket)
{
  int lane = threadIdx.x & 63;
  int k = blockIdx.x * 4 + (threadIdx.x >> 6);   // one wave per row
  u64 key[12];
#pragma unroll
  for (int i = 0; i < 12; ++i) {
    int j = lane + i * 64;
    uint u = __float_as_uint(fast[(size_t)k * KK + j]);
    uint s = (u & 0x80000000u) ? ~u : (u | 0x80000000u);
    key[i] = ((u64)s << 10) | (u64)(1023 - j);
  }
  for (int it = 0; it < CC; ++it) {
    u64 gm = key[0];
#pragma unroll
    for (int i = 1; i < 12; ++i) gm = (key[i] > gm) ? key[i] : gm;
    for (int msk = 32; msk > 0; msk >>= 1) {
      u64 o = shflx64(gm, msk);
      gm = (o > gm) ? o : gm;
    }
#pragma unroll
    for (int i = 0; i < 12; ++i) if (key[i] == gm) key[i] = 0;
    if (lane == 0) {
      uint s = (uint)(gm >> 10);
      uint u = (s & 0x80000000u) ? (s & 0x7fffffffu) : ~s;
      int j = 1023 - (int)(gm & 1023u);
      int r = k * CC + it;
      top_fast[r] = __uint_as_float(u);
      row_j[r] = j;
      row_bucket[r] = bucketd(k - j);
    }
  }
}

// ---------------------------------------------------------------------------
// K6: pair GEMM — exact R5 config (best measured: 240 µs). BM=128 x BN=256,
// 512 thr, 8 waves as 4m(32) x 2n(128), dbuf, 1 barrier/iter, LDS 49.5 KB,
// unpadded XOR-swizzled A and B (0 bank conflicts), pkmul via v_perm_b32.
// ---------------------------------------------------------------------------
__global__ __launch_bounds__(512, 4) void pair_mfma_k(
    const ushort* __restrict__ se_bf, const ushort* __restrict__ W1simT,
    const int* __restrict__ row_j, const int* __restrict__ row_bucket,
    const float* __restrict__ Ptgt, const float* __restrict__ Pant,
    const float* __restrict__ Pdist, const float* __restrict__ w2,
    float* __restrict__ slow)
{
  __shared__ __align__(16) ushort As[2][128 * 32];   // 16 KB
  __shared__ __align__(16) ushort Bs[2][256 * 32];   // 32 KB
  __shared__ int ks_s[128];
  __shared__ int js_s[128];
  __shared__ int bk_s[128];
  int tid = threadIdx.x;                 // 0..511
  int m0 = blockIdx.x * 128, n0 = blockIdx.y * 256;
  if (tid < 128) {
    int r = m0 + tid;
    ks_s[tid] = r / CC;
    js_s[tid] = row_j[r];
    bk_s[tid] = row_bucket[r];
  }
  __syncthreads();
  int lane = tid & 63, wid = tid >> 6;   // 8 waves
  int quad = lane >> 4, lr = lane & 15;
  int wm = (wid & 3) << 5;               // 0,32,64,96
  int wn = (wid >> 2) << 7;              // 0,128
  int ar0 = tid >> 2, aq = tid & 3;      // 128 A-rows, 4 lanes each
  const ushort* pk0 = se_bf + (size_t)ks_s[ar0] * SPAN + aq * 8;
  const ushort* pj0 = se_bf + (size_t)js_s[ar0] * SPAN + aq * 8;
  int gofs[2];
#pragma unroll
  for (int t = 0; t < 2; ++t) {
    int S = t * 512 + tid;               // 0..1023 -> 256 B-rows x 4 slots
    int r = S >> 2, p = S & 3;
    int q = p ^ ((r >> 1) & 3);
    gofs[t] = (n0 + r) * 32 + q * 8;
  }
  int awi0 = ar0 * 32 + (aq ^ ((ar0 >> 1) & 3)) * 8;

  {
    uint4 ka0 = *(const uint4*)(pk0);
    uint4 ja0 = *(const uint4*)(pj0);
#pragma unroll
    for (int t = 0; t < 2; ++t)
      dma16(W1simT + gofs[t], &Bs[0][(size_t)(t * 512 + tid) * 8]);
    *(uint4*)&As[0][awi0] = pkmul4(ka0, ja0);
  }
  __syncthreads();

  f32x4 acc[2][8] = {};
  for (int k0 = 0; k0 < SPAN; k0 += 32) {
    int buf = (k0 >> 5) & 1, nb = buf ^ 1;
    bool more = (k0 + 32) < SPAN;
    int k1 = more ? k0 + 32 : k0;
    uint4 ka0 = *(const uint4*)(pk0 + k1);
    uint4 ja0 = *(const uint4*)(pj0 + k1);
    if (more) {
      const ushort* sb = W1simT + (size_t)(k1 >> 5) * (NPAD * 32);
#pragma unroll
      for (int t = 0; t < 2; ++t)
        dma16(sb + gofs[t], &Bs[nb][(size_t)(t * 512 + tid) * 8]);
    }
    bf16x8 af[2], bfr[8];
#pragma unroll
    for (int mi = 0; mi < 2; ++mi) {
      int r = wm + mi * 16 + lr;
      int p = quad ^ ((r >> 1) & 3);
      af[mi] = *(const bf16x8*)&As[buf][r * 32 + p * 8];
    }
#pragma unroll
    for (int ni = 0; ni < 8; ++ni) {
      int r = wn + ni * 16 + lr;
      int p = quad ^ ((r >> 1) & 3);
      bfr[ni] = *(const bf16x8*)&Bs[buf][r * 32 + p * 8];
    }
#pragma unroll
    for (int ni = 0; ni < 8; ++ni)
#pragma unroll
      for (int mi = 0; mi < 2; ++mi)
        acc[mi][ni] = __builtin_amdgcn_mfma_f32_16x16x32_bf16(
            af[mi], bfr[ni], acc[mi][ni], 0, 0, 0);
    if (more) {
      *(uint4*)&As[nb][awi0] = pkmul4(ka0, ja0);
    }
    __syncthreads();
  }
  int nn[8]; float w2r[8]; bool nv[8];
#pragma unroll
  for (int ni = 0; ni < 8; ++ni) {
    nn[ni] = n0 + wn + ni * 16 + lr;
    nv[ni] = nn[ni] < HH;
    w2r[ni] = nv[ni] ? w2[nn[ni]] : 0.f;
  }
#pragma unroll
  for (int mi = 0; mi < 2; ++mi) {
#pragma unroll
    for (int reg = 0; reg < 4; ++reg) {
      int rl = wm + mi * 16 + quad * 4 + reg;
      int kk = ks_s[rl], jj = js_s[rl], bb = bk_s[rl];
      float s = 0.f;
#pragma unroll
      for (int ni = 0; ni < 8; ++ni) {
        if (nv[ni]) {
          float h = acc[mi][ni][reg] + Ptgt[(size_t)kk * HH + nn[ni]] +
                    Pant[(size_t)jj * HH + nn[ni]] +
                    Pdist[(size_t)bb * HH + nn[ni]];
          s += fmaxf(h, 0.f) * w2r[ni];
        }
      }
      s += __shfl_xor(s, 1); s += __shfl_xor(s, 2);
      s += __shfl_xor(s, 4); s += __shfl_xor(s, 8);
      if (lr == 0) atomicAdd(&slow[m0 + rl], s);
    }
  }
}

// ---------------------------------------------------------------------------
// K7: finalize (-inf -> -1e30)
// ---------------------------------------------------------------------------
__global__ void finalize_k(const float* __restrict__ slow,
                           const float* __restrict__ top_fast,
                           const float* __restrict__ b2, float* __restrict__ out)
{
  int t = blockIdx.x * 256 + threadIdx.x;
  if (t >= KK * (CC + 1)) return;
  int k = t / (CC + 1), col = t % (CC + 1);
  if (col == 0) {
    out[t] = 0.f;
  } else {
    int r = k * CC + col - 1;
    float v = slow[r] + b2[0] + top_fast[r];
    if (!isfinite(v)) v = -1.0e30f;
    out[t] = v;
  }
}

// ---------------------------------------------------------------------------
extern "C" void kernel_launch(void* const* d_in, const int* in_sizes, int n_in,
                              void* d_out, int out_size, void* d_ws, size_t ws_size,
                              hipStream_t stream)
{
  const float* doc        = (const float*)d_in[0];
  const float* doc1       = (const float*)d_in[1];
  const int*   starts     = (const int*)d_in[2];
  const int*   ends       = (const int*)d_in[3];
  const float* ms         = (const float*)d_in[4];
  const float* attn_w     = (const float*)d_in[5];
  const float* attn_b     = (const float*)d_in[6];
  const float* coarse_w   = (const float*)d_in[7];
  const float* coarse_b   = (const float*)d_in[8];
  const float* dist_prior = (const float*)d_in[9];
  const float* dist_w     = (const float*)d_in[10];
  const float* dist_b     = (const float*)d_in[11];
  const float* top_dist   = (const float*)d_in[12];
  const float* W1         = (const float*)d_in[13];
  const float* b1         = (const float*)d_in[14];
  const float* w2         = (const float*)d_in[15];
  const float* b2         = (const float*)d_in[16];
  float* out = (float*)d_out;

  char* ws = (char*)d_ws;
  size_t off = 0;
  auto alloc = [&](size_t bytes) { void* p = ws + off; off = (off + bytes + 1023) & ~(size_t)1023; return p; };
  float*  hybrid     = (float*)alloc((size_t)WTOK * DD * 4);
  float*  tok_attn   = (float*)alloc((size_t)WTOK * 4);
  ushort* se_bf      = (ushort*)alloc((size_t)KK * SPAN * 2 + 4096);
  ushort* src_bf     = (ushort*)alloc((size_t)KK * SPAN * 2 + 4096);
  float*  fast       = (float*)alloc((size_t)KK * KK * 4);
  float*  Ptgt       = (float*)alloc((size_t)KK * HH * 4);
  float*  Pant       = (float*)alloc((size_t)KK * HH * 4);
  float*  Pdist      = (float*)alloc((size_t)10 * HH * 4);
  float*  dist_score = (float*)alloc(64);
  float*  top_fast   = (float*)alloc((size_t)KK * CC * 4);
  int*    row_j      = (int*)alloc((size_t)KK * CC * 4);
  int*    row_bucket = (int*)alloc((size_t)KK * CC * 4);
  float*  slow       = (float*)alloc((size_t)KK * CC * 4);
  ushort* BigT       = (ushort*)alloc((size_t)NBIG * SPAN * 2 + 4096);   // k-tiled [72][NBIG][32]
  ushort* W1simT     = (ushort*)alloc((size_t)NPAD * SPAN * 2 + 4096);   // k-tiled [72][NPAD][32]
  (void)ws_size; (void)in_sizes; (void)n_in; (void)out_size;

  // 1. fused prep: transposes + dist setup + slow init + hybrid/token-attn
  prep_k<<<PB_TOTAL, 256, 0, stream>>>(coarse_w, W1, dist_prior, dist_w,
                                       dist_b, top_dist, doc, doc1, attn_w,
                                       attn_b, BigT, W1simT, dist_score,
                                       Pdist, slow, hybrid, tok_attn);
  // 2. span embeddings
  span_emb_k<<<KK, 256, 0, stream>>>(doc, hybrid, tok_attn, starts, ends, se_bf);
  // 3. src_bf / Ptgt(+b1) / Pant, 64x128 tiles, dbuf BK=64
  {
    dim3 g(KK / 64, NBIG / 128);
    gemm_combined_k<<<g, 256, 0, stream>>>(se_bf, BigT, coarse_b, b1,
                                           src_bf, Ptgt, Pant);
  }
  // 4. fast = src @ se^T with fused epilogue, 64x64 tiles, dbuf BK=64
  {
    dim3 g(KK / 64, KK / 64);
    gemm_fast_k<<<g, 256, 0, stream>>>(src_bf, se_bf, ms, dist_score, fast);
  }
  // 5. top-50, wave-per-row, zero barriers
  topk_k<<<KK / 4, 256, 0, stream>>>(fast, top_fast, row_j, row_bucket);
  // 6. fused pair GEMM + epilogue, R5 config (BM=128 x BN=256, 512 thr)
  {
    dim3 g((KK * CC) / 128, NPAD / 256);
    pair_mfma_k<<<g, 512, 0, stream>>>(se_bf, W1simT, row_j, row_bucket,
                                       Ptgt, Pant, Pdist, w2, slow);
  }
  // 7. output
  finalize_k<<<(KK * (CC + 1) + 255) / 256, 256, 0, stream>>>(slow, top_fast, b2, out);
}

// Round 10
// 472.041 us; speedup vs baseline: 1.1388x; 1.0103x over previous
//
#include <hip/hip_runtime.h>
#include <math.h>

// W=4096, D=768, K=768, SPAN=3D=2304, F=20, H=1000, PAIR=6932, C=50.
#define WTOK 4096
#define DD   768
#define KK   768
#define SPAN 2304
#define HH   1000
#define CC   50
#define NPAD 1024   // HH padded for pair-GEMM tiles
#define NBIG 4352   // 2304 (coarse) + 1024 (tgt) + 1024 (ant)

typedef __attribute__((ext_vector_type(8))) short bf16x8;
typedef __attribute__((ext_vector_type(4))) float f32x4;
typedef unsigned short ushort;
typedef unsigned int uint;
typedef unsigned long long u64;

__device__ __forceinline__ int bucketd(int d) {
  int l = (d >= 1) ? (31 - __clz(d)) : 0;
  int v = (d <= 4) ? d : (l + 3);
  return min(max(v, 0), 9);
}
__device__ __forceinline__ ushort f2bf(float f) {
  uint u = __float_as_uint(f);
  return (ushort)((u + 0x7fffu + ((u >> 16) & 1u)) >> 16);  // RNE
}
// packed bf16x2 elementwise product, truncating round.
__device__ __forceinline__ uint pkmul_t(uint a, uint b) {
  float lo = __uint_as_float(a << 16) * __uint_as_float(b << 16);
  float hi = __uint_as_float(a & 0xffff0000u) * __uint_as_float(b & 0xffff0000u);
  return __builtin_amdgcn_perm(__float_as_uint(hi), __float_as_uint(lo), 0x07060302u);
}
__device__ __forceinline__ uint4 pkmul4(uint4 a, uint4 b) {
  uint4 r;
  r.x = pkmul_t(a.x, b.x); r.y = pkmul_t(a.y, b.y);
  r.z = pkmul_t(a.z, b.z); r.w = pkmul_t(a.w, b.w);
  return r;
}
// async global->LDS DMA, 16 B per lane
__device__ __forceinline__ void dma16(const ushort* g, ushort* l) {
  __builtin_amdgcn_global_load_lds(
      (const __attribute__((address_space(1))) void*)g,
      (__attribute__((address_space(3))) void*)l, 16, 0, 0);
}
// 64-bit wave shfl_xor via two 32-bit shfls
__device__ __forceinline__ u64 shflx64(u64 v, int msk) {
  uint lo = (uint)v, hi = (uint)(v >> 32);
  lo = (uint)__shfl_xor((int)lo, msk, 64);
  hi = (uint)__shfl_xor((int)hi, msk, 64);
  return ((u64)hi << 32) | lo;
}

// ---------------------------------------------------------------------------
// K0: fused prep: transposes (k-tiled [72][rows][32], 64x64 tiles), dist
// setup, slow init, hybrid/token-attn tail.
// ---------------------------------------------------------------------------
#define PB_COARSE 1296                                 // (2304/64)^2
#define PB_W 576                                       // (1024/64)*(2304/64)
#define PB_SETUP_BASE (PB_COARSE + 3 * PB_W)          // 3024
#define PB_SLOW_BASE  (PB_SETUP_BASE + 40)            // 3064
#define PB_HYB_BASE   (PB_SLOW_BASE + 150)            // 3214
#define PB_TOTAL      (PB_HYB_BASE + WTOK)            // 7310

__global__ __launch_bounds__(256) void prep_k(
    const float* __restrict__ coarse_w, const float* __restrict__ W1,
    const float* __restrict__ dist_prior, const float* __restrict__ dist_w,
    const float* __restrict__ dist_b, const float* __restrict__ top_dist,
    const float* __restrict__ doc, const float* __restrict__ doc1,
    const float* __restrict__ attn_w, const float* __restrict__ attn_b,
    ushort* __restrict__ BigT, ushort* __restrict__ W1simT,
    float* __restrict__ dist_score, float* __restrict__ Pdist,
    float* __restrict__ slow, float* __restrict__ hybrid,
    float* __restrict__ tok_attn)
{
  int bid = blockIdx.x;
  int tid = threadIdx.x;
  if (bid >= PB_HYB_BASE) {
    int w = bid - PB_HYB_BASE;
    float part = 0.f;
    for (int d = tid; d < DD; d += 256) {
      float h = 0.5f * doc[(long)w * DD + d] + 0.5f * doc1[(long)w * DD + d];
      hybrid[(long)w * DD + d] = h;
      part += h * attn_w[d];
    }
    for (int off = 32; off > 0; off >>= 1) part += __shfl_down(part, off, 64);
    __shared__ float ws4[4];
    if ((tid & 63) == 0) ws4[tid >> 6] = part;
    __syncthreads();
    if (tid == 0) tok_attn[w] = ws4[0] + ws4[1] + ws4[2] + ws4[3] + attn_b[0];
    return;
  }
  if (bid >= PB_SLOW_BASE) {
    int t = (bid - PB_SLOW_BASE) * 256 + tid;
    if (t < KK * CC) slow[t] = 0.f;
    return;
  }
  if (bid >= PB_SETUP_BASE) {
    int t = (bid - PB_SETUP_BASE) * 256 + tid;
    if (t < 10) {
      float s = dist_b[0];
      for (int f = 0; f < 20; ++f) s += dist_prior[t * 20 + f] * dist_w[f];
      dist_score[t] = s;
    }
    if (t < 10 * HH) {
      int b = t / HH, h = t % HH;
      float s = 0.f;
      for (int f = 0; f < 20; ++f)
        s += top_dist[b * 20 + f] * W1[(long)(6912 + f) * HH + h];
      Pdist[t] = s;
    }
    return;
  }
  const float* in; int ldin, Cin, nbase, NBrows; ushort* out; int idx;
  int xt;
  if (bid < PB_COARSE) {
    idx = bid; in = coarse_w; ldin = SPAN; Cin = SPAN; nbase = 0;
    NBrows = NBIG; out = BigT; xt = SPAN / 64;
  } else {
    idx = bid - PB_COARSE;
    int region = idx / PB_W;  // 0=tgt 1=ant 2=sim
    idx = idx % PB_W;
    if (region == 0) { in = W1; nbase = 2304; NBrows = NBIG; out = BigT; }
    else if (region == 1) { in = W1 + (size_t)SPAN * HH; nbase = 3328; NBrows = NBIG; out = BigT; }
    else { in = W1 + (size_t)2 * SPAN * HH; nbase = 0; NBrows = NPAD; out = W1simT; }
    ldin = HH; Cin = HH; xt = NPAD / 64;
  }
  {
    int bx = idx % xt, by = idx / xt;
    __shared__ float tile[64][65];
    int n0 = bx * 64, p0 = by * 64;
    int tx = tid & 63, ty = tid >> 6;   // 4 rows per iter
    for (int i = ty; i < 64; i += 4) {
      int p = p0 + i, n = n0 + tx;
      tile[i][tx] = (n < Cin) ? in[(long)p * ldin + n] : 0.f;
    }
    __syncthreads();
    size_t obase = (size_t)(((p0 + tx) >> 5)) * NBrows * 32 + (tx & 31);
    for (int i = ty; i < 64; i += 4) {
      int n = n0 + i;
      out[obase + (size_t)(nbase + n) * 32] = f2bf(tile[tx][i]);
    }
  }
}

// ---------------------------------------------------------------------------
// K2: span embeddings -> se_bf [KK][SPAN] bf16
// ---------------------------------------------------------------------------
__global__ __launch_bounds__(256) void span_emb_k(
    const float* __restrict__ doc, const float* __restrict__ hybrid,
    const float* __restrict__ tok_attn, const int* __restrict__ starts,
    const int* __restrict__ ends, ushort* __restrict__ se_bf)
{
  int k = blockIdx.x;
  int s = starts[k], e = ends[k];
  int len = e - s + 1;  // <= 30
  int tid = threadIdx.x;
  __shared__ float p_s[32];
  if (tid < 32) {
    float v = (tid < len) ? tok_attn[s + tid] : -INFINITY;
    float m = v;
    for (int msk = 16; msk >= 1; msk >>= 1) m = fmaxf(m, __shfl_xor(m, msk, 32));
    float pe = (tid < len) ? expf(v - m) : 0.f;
    float Z = pe;
    for (int msk = 16; msk >= 1; msk >>= 1) Z += __shfl_xor(Z, msk, 32);
    p_s[tid] = pe / Z;
  }
  __syncthreads();
  for (int d = tid; d < DD; d += 256) {
    float h = 0.f;
    for (int t = 0; t < len; ++t) h += p_s[t] * hybrid[(long)(s + t) * DD + d];
    se_bf[(long)k * SPAN + d]          = f2bf(doc[(long)s * DD + d]);
    se_bf[(long)k * SPAN + DD + d]     = f2bf(doc[(long)e * DD + d]);
    se_bf[(long)k * SPAN + 2 * DD + d] = f2bf(h);
  }
}

// ---------------------------------------------------------------------------
// K3: combined NT GEMM — retiled 64x64 (was 64x128): grid 12x68 = 816 blocks
// (3.2/CU, all co-resident; was 408 = 1.6/CU, parallelism-starved — this
// stage is latency-bound, not throughput-bound). B traffic invariant under
// the split (240 MB either way); A panel is 3.5 MB total -> L2-resident so
// the extra A refetch is free. dbuf, BK=64, per-acc MFMA k-order unchanged
// -> bit-identical.
// ---------------------------------------------------------------------------
__global__ __launch_bounds__(256) void gemm_combined_k(
    const ushort* __restrict__ A, const ushort* __restrict__ B,
    const float* __restrict__ coarse_b, const float* __restrict__ b1,
    ushort* __restrict__ src_bf, float* __restrict__ Ptgt,
    float* __restrict__ Pant)
{
  __shared__ __align__(16) ushort As[2][64 * 72];      // 18.4 KB
  __shared__ __align__(16) ushort Bs[2][2][64 * 32];   // 16 KB
  int tid = threadIdx.x;
  int m0 = blockIdx.x * 64, n0 = blockIdx.y * 64;
  int lane = tid & 63, wid = tid >> 6;
  int quad = lane >> 4, lr = lane & 15;
  int wm = (wid & 1) << 5, wn = (wid >> 1) << 5;
  int arow = tid >> 2, aq = tid & 3;     // A: 64 rows, 4 lanes each
  int gofs;
  {
    int r = tid >> 2, p = tid & 3;
    int q = p ^ ((r >> 1) & 3);
    gofs = (n0 + r) * 32 + q * 8;
  }
  const ushort* ga = A + (size_t)(m0 + arow) * SPAN + aq * 8;
  {
    uint4 alo = *(const uint4*)(ga);
    uint4 ahi = *(const uint4*)(ga + 32);
#pragma unroll
    for (int kh = 0; kh < 2; ++kh)
      dma16(B + (size_t)kh * (NBIG * 32) + gofs, &Bs[0][kh][(size_t)tid * 8]);
    *(uint4*)&As[0][arow * 72 + aq * 8] = alo;
    *(uint4*)&As[0][arow * 72 + 32 + aq * 8] = ahi;
  }
  __syncthreads();
  f32x4 acc[2][2] = {};
  for (int s = 0; s < 36; ++s) {
    int buf = s & 1, nb = buf ^ 1;
    bool more = (s + 1) < 36;
    uint4 alo, ahi;
    if (more) {
      alo = *(const uint4*)(ga + (s + 1) * 64);
      ahi = *(const uint4*)(ga + (s + 1) * 64 + 32);
#pragma unroll
      for (int kh = 0; kh < 2; ++kh)
        dma16(B + (size_t)(2 * (s + 1) + kh) * (NBIG * 32) + gofs,
              &Bs[nb][kh][(size_t)tid * 8]);
    }
    bf16x8 af[2][2], bfr[2][2];
#pragma unroll
    for (int mi = 0; mi < 2; ++mi)
#pragma unroll
      for (int kh = 0; kh < 2; ++kh)
        af[mi][kh] = *(const bf16x8*)&As[buf][(wm + mi * 16 + lr) * 72 + kh * 32 + quad * 8];
#pragma unroll
    for (int ni = 0; ni < 2; ++ni) {
      int r = wn + ni * 16 + lr;
      int p = quad ^ ((r >> 1) & 3);
#pragma unroll
      for (int kh = 0; kh < 2; ++kh)
        bfr[ni][kh] = *(const bf16x8*)&Bs[buf][kh][r * 32 + p * 8];
    }
#pragma unroll
    for (int kh = 0; kh < 2; ++kh)
#pragma unroll
      for (int mi = 0; mi < 2; ++mi)
#pragma unroll
        for (int ni = 0; ni < 2; ++ni)
          acc[mi][ni] = __builtin_amdgcn_mfma_f32_16x16x32_bf16(
              af[mi][kh], bfr[ni][kh], acc[mi][ni], 0, 0, 0);
    if (more) {
      *(uint4*)&As[nb][arow * 72 + aq * 8] = alo;
      *(uint4*)&As[nb][arow * 72 + 32 + aq * 8] = ahi;
    }
    __syncthreads();
  }
#pragma unroll
  for (int mi = 0; mi < 2; ++mi)
#pragma unroll
    for (int ni = 0; ni < 2; ++ni) {
      f32x4 c = acc[mi][ni];
#pragma unroll
      for (int reg = 0; reg < 4; ++reg) {
        int gm = m0 + wm + mi * 16 + quad * 4 + reg;
        int g = n0 + wn + ni * 16 + lr;
        float v = c[reg];
        if (g < 2304) {
          src_bf[(size_t)gm * SPAN + g] = f2bf(v + coarse_b[g]);
        } else if (g < 3328) {
          int n = g - 2304;
          if (n < HH) Ptgt[(size_t)gm * HH + n] = v + b1[n];  // b1 folded in
        } else {
          int n = g - 3328;
          if (n < HH) Pant[(size_t)gm * HH + n] = v;
        }
      }
    }
}

// ---------------------------------------------------------------------------
// K4: fast GEMM (src @ se^T), 64x64 tiles, dbuf BK=64 — upper-triangle
// blocks (n0 > m0: all outputs fail gn < gm) skip the entire K-loop and
// just store -inf (value-identical to computing then discarding). 66 of
// 144 blocks become trivial.
// ---------------------------------------------------------------------------
__global__ __launch_bounds__(256) void gemm_fast_k(
    const ushort* __restrict__ A, const ushort* __restrict__ B,
    const float* __restrict__ ms, const float* __restrict__ dist_score,
    float* __restrict__ fast)
{
  __shared__ __align__(16) ushort As[2][64 * 72];
  __shared__ __align__(16) ushort Bs[2][64 * 72];
  int tid = threadIdx.x;
  int m0 = blockIdx.x * 64, n0 = blockIdx.y * 64;
  int lane = tid & 63, wid = tid >> 6;
  int quad = lane >> 4, lr = lane & 15;
  int wm = (wid & 1) << 5, wn = (wid >> 1) << 5;
  if (n0 > m0) {  // fully upper-triangle: every gn >= n0 > m0+63 >= gm
#pragma unroll
    for (int mi = 0; mi < 2; ++mi)
#pragma unroll
      for (int ni = 0; ni < 2; ++ni)
#pragma unroll
        for (int reg = 0; reg < 4; ++reg) {
          int gm = m0 + wm + mi * 16 + quad * 4 + reg;
          int gn = n0 + wn + ni * 16 + lr;
          fast[(size_t)gm * KK + gn] = -INFINITY;
        }
    return;
  }
  int row = tid >> 2, aq = tid & 3;
  const ushort* ga = A + (size_t)(m0 + row) * SPAN + aq * 8;
  const ushort* gb = B + (size_t)(n0 + row) * SPAN + aq * 8;
  {
    uint4 a0 = *(const uint4*)(ga);
    uint4 a1 = *(const uint4*)(ga + 32);
    uint4 b0 = *(const uint4*)(gb);
    uint4 b1v = *(const uint4*)(gb + 32);
    *(uint4*)&As[0][row * 72 + aq * 8] = a0;
    *(uint4*)&As[0][row * 72 + 32 + aq * 8] = a1;
    *(uint4*)&Bs[0][row * 72 + aq * 8] = b0;
    *(uint4*)&Bs[0][row * 72 + 32 + aq * 8] = b1v;
  }
  __syncthreads();
  f32x4 acc[2][2] = {};
  for (int s = 0; s < 36; ++s) {
    int buf = s & 1, nb = buf ^ 1;
    bool more = (s + 1) < 36;
    uint4 a0, a1, b0, b1v;
    if (more) {
      a0 = *(const uint4*)(ga + (s + 1) * 64);
      a1 = *(const uint4*)(ga + (s + 1) * 64 + 32);
      b0 = *(const uint4*)(gb + (s + 1) * 64);
      b1v = *(const uint4*)(gb + (s + 1) * 64 + 32);
    }
    bf16x8 af[2][2], bfr[2][2];
#pragma unroll
    for (int mi = 0; mi < 2; ++mi)
#pragma unroll
      for (int kh = 0; kh < 2; ++kh)
        af[mi][kh] = *(const bf16x8*)&As[buf][(wm + mi * 16 + lr) * 72 + kh * 32 + quad * 8];
#pragma unroll
    for (int ni = 0; ni < 2; ++ni)
#pragma unroll
      for (int kh = 0; kh < 2; ++kh)
        bfr[ni][kh] = *(const bf16x8*)&Bs[buf][(wn + ni * 16 + lr) * 72 + kh * 32 + quad * 8];
#pragma unroll
    for (int kh = 0; kh < 2; ++kh)
#pragma unroll
      for (int mi = 0; mi < 2; ++mi)
#pragma unroll
        for (int ni = 0; ni < 2; ++ni)
          acc[mi][ni] = __builtin_amdgcn_mfma_f32_16x16x32_bf16(
              af[mi][kh], bfr[ni][kh], acc[mi][ni], 0, 0, 0);
    if (more) {
      *(uint4*)&As[nb][row * 72 + aq * 8] = a0;
      *(uint4*)&As[nb][row * 72 + 32 + aq * 8] = a1;
      *(uint4*)&Bs[nb][row * 72 + aq * 8] = b0;
      *(uint4*)&Bs[nb][row * 72 + 32 + aq * 8] = b1v;
    }
    __syncthreads();
  }
#pragma unroll
  for (int mi = 0; mi < 2; ++mi)
#pragma unroll
    for (int ni = 0; ni < 2; ++ni) {
      f32x4 c = acc[mi][ni];
#pragma unroll
      for (int reg = 0; reg < 4; ++reg) {
        int gm = m0 + wm + mi * 16 + quad * 4 + reg;
        int gn = n0 + wn + ni * 16 + lr;
        float v;
        if (gn < gm) {
          v = c[reg] + ms[gm] + ms[gn] + dist_score[bucketd(gm - gn)];
        } else {
          v = -INFINITY;
        }
        fast[(size_t)gm * KK + gn] = v;
      }
    }
}

// ---------------------------------------------------------------------------
// K5: exact top-50 — zero-barrier wave-per-row (R8, proven). Keys
// (sortable_float << 10) | (1023 - j): order == (value desc, index asc).
// ---------------------------------------------------------------------------
__global__ __launch_bounds__(256) void topk_k(
    const float* __restrict__ fast, float* __restrict__ top_fast,
    int* __restrict__ row_j, int* __restrict__ row_bucket)
{
  int lane = threadIdx.x & 63;
  int k = blockIdx.x * 4 + (threadIdx.x >> 6);   // one wave per row
  u64 key[12];
#pragma unroll
  for (int i = 0; i < 12; ++i) {
    int j = lane + i * 64;
    uint u = __float_as_uint(fast[(size_t)k * KK + j]);
    uint s = (u & 0x80000000u) ? ~u : (u | 0x80000000u);
    key[i] = ((u64)s << 10) | (u64)(1023 - j);
  }
  for (int it = 0; it < CC; ++it) {
    u64 gm = key[0];
#pragma unroll
    for (int i = 1; i < 12; ++i) gm = (key[i] > gm) ? key[i] : gm;
    for (int msk = 32; msk > 0; msk >>= 1) {
      u64 o = shflx64(gm, msk);
      gm = (o > gm) ? o : gm;
    }
#pragma unroll
    for (int i = 0; i < 12; ++i) if (key[i] == gm) key[i] = 0;
    if (lane == 0) {
      uint s = (uint)(gm >> 10);
      uint u = (s & 0x80000000u) ? (s & 0x7fffffffu) : ~s;
      int j = 1023 - (int)(gm & 1023u);
      int r = k * CC + it;
      top_fast[r] = __uint_as_float(u);
      row_j[r] = j;
      row_bucket[r] = bucketd(k - j);
    }
  }
}

// ---------------------------------------------------------------------------
// K6: pair GEMM — exact R5 config (best measured: 240 µs). BM=128 x BN=256,
// 512 thr, 8 waves as 4m(32) x 2n(128), dbuf, 1 barrier/iter, LDS 49.5 KB,
// unpadded XOR-swizzled A and B (0 bank conflicts), pkmul via v_perm_b32.
// ---------------------------------------------------------------------------
__global__ __launch_bounds__(512, 4) void pair_mfma_k(
    const ushort* __restrict__ se_bf, const ushort* __restrict__ W1simT,
    const int* __restrict__ row_j, const int* __restrict__ row_bucket,
    const float* __restrict__ Ptgt, const float* __restrict__ Pant,
    const float* __restrict__ Pdist, const float* __restrict__ w2,
    float* __restrict__ slow)
{
  __shared__ __align__(16) ushort As[2][128 * 32];   // 16 KB
  __shared__ __align__(16) ushort Bs[2][256 * 32];   // 32 KB
  __shared__ int ks_s[128];
  __shared__ int js_s[128];
  __shared__ int bk_s[128];
  int tid = threadIdx.x;                 // 0..511
  int m0 = blockIdx.x * 128, n0 = blockIdx.y * 256;
  if (tid < 128) {
    int r = m0 + tid;
    ks_s[tid] = r / CC;
    js_s[tid] = row_j[r];
    bk_s[tid] = row_bucket[r];
  }
  __syncthreads();
  int lane = tid & 63, wid = tid >> 6;   // 8 waves
  int quad = lane >> 4, lr = lane & 15;
  int wm = (wid & 3) << 5;               // 0,32,64,96
  int wn = (wid >> 2) << 7;              // 0,128
  int ar0 = tid >> 2, aq = tid & 3;      // 128 A-rows, 4 lanes each
  const ushort* pk0 = se_bf + (size_t)ks_s[ar0] * SPAN + aq * 8;
  const ushort* pj0 = se_bf + (size_t)js_s[ar0] * SPAN + aq * 8;
  int gofs[2];
#pragma unroll
  for (int t = 0; t < 2; ++t) {
    int S = t * 512 + tid;               // 0..1023 -> 256 B-rows x 4 slots
    int r = S >> 2, p = S & 3;
    int q = p ^ ((r >> 1) & 3);
    gofs[t] = (n0 + r) * 32 + q * 8;
  }
  int awi0 = ar0 * 32 + (aq ^ ((ar0 >> 1) & 3)) * 8;

  {
    uint4 ka0 = *(const uint4*)(pk0);
    uint4 ja0 = *(const uint4*)(pj0);
#pragma unroll
    for (int t = 0; t < 2; ++t)
      dma16(W1simT + gofs[t], &Bs[0][(size_t)(t * 512 + tid) * 8]);
    *(uint4*)&As[0][awi0] = pkmul4(ka0, ja0);
  }
  __syncthreads();

  f32x4 acc[2][8] = {};
  for (int k0 = 0; k0 < SPAN; k0 += 32) {
    int buf = (k0 >> 5) & 1, nb = buf ^ 1;
    bool more = (k0 + 32) < SPAN;
    int k1 = more ? k0 + 32 : k0;
    uint4 ka0 = *(const uint4*)(pk0 + k1);
    uint4 ja0 = *(const uint4*)(pj0 + k1);
    if (more) {
      const ushort* sb = W1simT + (size_t)(k1 >> 5) * (NPAD * 32);
#pragma unroll
      for (int t = 0; t < 2; ++t)
        dma16(sb + gofs[t], &Bs[nb][(size_t)(t * 512 + tid) * 8]);
    }
    bf16x8 af[2], bfr[8];
#pragma unroll
    for (int mi = 0; mi < 2; ++mi) {
      int r = wm + mi * 16 + lr;
      int p = quad ^ ((r >> 1) & 3);
      af[mi] = *(const bf16x8*)&As[buf][r * 32 + p * 8];
    }
#pragma unroll
    for (int ni = 0; ni < 8; ++ni) {
      int r = wn + ni * 16 + lr;
      int p = quad ^ ((r >> 1) & 3);
      bfr[ni] = *(const bf16x8*)&Bs[buf][r * 32 + p * 8];
    }
#pragma unroll
    for (int ni = 0; ni < 8; ++ni)
#pragma unroll
      for (int mi = 0; mi < 2; ++mi)
        acc[mi][ni] = __builtin_amdgcn_mfma_f32_16x16x32_bf16(
            af[mi], bfr[ni], acc[mi][ni], 0, 0, 0);
    if (more) {
      *(uint4*)&As[nb][awi0] = pkmul4(ka0, ja0);
    }
    __syncthreads();
  }
  int nn[8]; float w2r[8]; bool nv[8];
#pragma unroll
  for (int ni = 0; ni < 8; ++ni) {
    nn[ni] = n0 + wn + ni * 16 + lr;
    nv[ni] = nn[ni] < HH;
    w2r[ni] = nv[ni] ? w2[nn[ni]] : 0.f;
  }
#pragma unroll
  for (int mi = 0; mi < 2; ++mi) {
#pragma unroll
    for (int reg = 0; reg < 4; ++reg) {
      int rl = wm + mi * 16 + quad * 4 + reg;
      int kk = ks_s[rl], jj = js_s[rl], bb = bk_s[rl];
      float s = 0.f;
#pragma unroll
      for (int ni = 0; ni < 8; ++ni) {
        if (nv[ni]) {
          float h = acc[mi][ni][reg] + Ptgt[(size_t)kk * HH + nn[ni]] +
                    Pant[(size_t)jj * HH + nn[ni]] +
                    Pdist[(size_t)bb * HH + nn[ni]];
          s += fmaxf(h, 0.f) * w2r[ni];
        }
      }
      s += __shfl_xor(s, 1); s += __shfl_xor(s, 2);
      s += __shfl_xor(s, 4); s += __shfl_xor(s, 8);
      if (lr == 0) atomicAdd(&slow[m0 + rl], s);
    }
  }
}

// ---------------------------------------------------------------------------
// K7: finalize (-inf -> -1e30)
// ---------------------------------------------------------------------------
__global__ void finalize_k(const float* __restrict__ slow,
                           const float* __restrict__ top_fast,
                           const float* __restrict__ b2, float* __restrict__ out)
{
  int t = blockIdx.x * 256 + threadIdx.x;
  if (t >= KK * (CC + 1)) return;
  int k = t / (CC + 1), col = t % (CC + 1);
  if (col == 0) {
    out[t] = 0.f;
  } else {
    int r = k * CC + col - 1;
    float v = slow[r] + b2[0] + top_fast[r];
    if (!isfinite(v)) v = -1.0e30f;
    out[t] = v;
  }
}

// ---------------------------------------------------------------------------
extern "C" void kernel_launch(void* const* d_in, const int* in_sizes, int n_in,
                              void* d_out, int out_size, void* d_ws, size_t ws_size,
                              hipStream_t stream)
{
  const float* doc        = (const float*)d_in[0];
  const float* doc1       = (const float*)d_in[1];
  const int*   starts     = (const int*)d_in[2];
  const int*   ends       = (const int*)d_in[3];
  const float* ms         = (const float*)d_in[4];
  const float* attn_w     = (const float*)d_in[5];
  const float* attn_b     = (const float*)d_in[6];
  const float* coarse_w   = (const float*)d_in[7];
  const float* coarse_b   = (const float*)d_in[8];
  const float* dist_prior = (const float*)d_in[9];
  const float* dist_w     = (const float*)d_in[10];
  const float* dist_b     = (const float*)d_in[11];
  const float* top_dist   = (const float*)d_in[12];
  const float* W1         = (const float*)d_in[13];
  const float* b1         = (const float*)d_in[14];
  const float* w2         = (const float*)d_in[15];
  const float* b2         = (const float*)d_in[16];
  float* out = (float*)d_out;

  char* ws = (char*)d_ws;
  size_t off = 0;
  auto alloc = [&](size_t bytes) { void* p = ws + off; off = (off + bytes + 1023) & ~(size_t)1023; return p; };
  float*  hybrid     = (float*)alloc((size_t)WTOK * DD * 4);
  float*  tok_attn   = (float*)alloc((size_t)WTOK * 4);
  ushort* se_bf      = (ushort*)alloc((size_t)KK * SPAN * 2 + 4096);
  ushort* src_bf     = (ushort*)alloc((size_t)KK * SPAN * 2 + 4096);
  float*  fast       = (float*)alloc((size_t)KK * KK * 4);
  float*  Ptgt       = (float*)alloc((size_t)KK * HH * 4);
  float*  Pant       = (float*)alloc((size_t)KK * HH * 4);
  float*  Pdist      = (float*)alloc((size_t)10 * HH * 4);
  float*  dist_score = (float*)alloc(64);
  float*  top_fast   = (float*)alloc((size_t)KK * CC * 4);
  int*    row_j      = (int*)alloc((size_t)KK * CC * 4);
  int*    row_bucket = (int*)alloc((size_t)KK * CC * 4);
  float*  slow       = (float*)alloc((size_t)KK * CC * 4);
  ushort* BigT       = (ushort*)alloc((size_t)NBIG * SPAN * 2 + 4096);   // k-tiled [72][NBIG][32]
  ushort* W1simT     = (ushort*)alloc((size_t)NPAD * SPAN * 2 + 4096);   // k-tiled [72][NPAD][32]
  (void)ws_size; (void)in_sizes; (void)n_in; (void)out_size;

  // 1. fused prep: transposes + dist setup + slow init + hybrid/token-attn
  prep_k<<<PB_TOTAL, 256, 0, stream>>>(coarse_w, W1, dist_prior, dist_w,
                                       dist_b, top_dist, doc, doc1, attn_w,
                                       attn_b, BigT, W1simT, dist_score,
                                       Pdist, slow, hybrid, tok_attn);
  // 2. span embeddings
  span_emb_k<<<KK, 256, 0, stream>>>(doc, hybrid, tok_attn, starts, ends, se_bf);
  // 3. src_bf / Ptgt(+b1) / Pant, 64x64 tiles (816 blocks, 3.2/CU), dbuf BK=64
  {
    dim3 g(KK / 64, NBIG / 64);
    gemm_combined_k<<<g, 256, 0, stream>>>(se_bf, BigT, coarse_b, b1,
                                           src_bf, Ptgt, Pant);
  }
  // 4. fast = src @ se^T with fused epilogue, 64x64 tiles, dbuf BK=64,
  //    upper-triangle blocks trivial
  {
    dim3 g(KK / 64, KK / 64);
    gemm_fast_k<<<g, 256, 0, stream>>>(src_bf, se_bf, ms, dist_score, fast);
  }
  // 5. top-50, wave-per-row, zero barriers
  topk_k<<<KK / 4, 256, 0, stream>>>(fast, top_fast, row_j, row_bucket);
  // 6. fused pair GEMM + epilogue, R5 config (BM=128 x BN=256, 512 thr)
  {
    dim3 g((KK * CC) / 128, NPAD / 256);
    pair_mfma_k<<<g, 512, 0, stream>>>(se_bf, W1simT, row_j, row_bucket,
                                       Ptgt, Pant, Pdist, w2, slow);
  }
  // 7. output
  finalize_k<<<(KK * (CC + 1) + 255) / 256, 256, 0, stream>>>(slow, top_fast, b2, out);
}